// Round 12
// baseline (292.135 us; speedup 1.0000x reference)
//
#include <hip/hip_runtime.h>
#include <math.h>

#define N_NODES 50000
#define N_EDGES 800000
#define EPS_F 1e-30f
#define N_TILES 782     // ceil(N_NODES/64)  (pgemm blocks)
#define N_CHUNKS 196    // ceil(N_NODES/256) (scan chunks)

typedef __bf16 bf16x8 __attribute__((ext_vector_type(8)));
typedef __bf16 bf16x4 __attribute__((ext_vector_type(4)));
typedef float  f32x4  __attribute__((ext_vector_type(4)));

#define STR1 136   // 128-wide bf16 tile row stride (fallback kernel)
#define STR2 72    // 64-wide bf16 tile row stride (144B)

// 1-ulp hardware reciprocal: avoids the IEEE div sequence (~10 VALU ops)
__device__ __forceinline__ float fast_rcp(float x) {
    float r;
    asm("v_rcp_f32 %0, %1" : "=v"(r) : "v"(x));
    return r;
}

__device__ __forceinline__ float silu_f(float x) {
    return x * fast_rcp(1.0f + __expf(-x));
}

__device__ __forceinline__ bf16x8 cvt8(float4 u0, float4 u1) {
    return (bf16x8){(__bf16)u0.x, (__bf16)u0.y, (__bf16)u0.z, (__bf16)u0.w,
                    (__bf16)u1.x, (__bf16)u1.y, (__bf16)u1.z, (__bf16)u1.w};
}

// ---------------- fused prologue: [pgemm tiles | weight pack + co4 + histogram] ----------------
__global__ void fused_prep(const float* __restrict__ node_feat,
                           const float* __restrict__ coord,
                           const int* __restrict__ dst,
                           const float* __restrict__ We1,   // [129][64] f32
                           const float* __restrict__ be1,
                           const float* __restrict__ We2,
                           const float* __restrict__ Wx1,
                           const float* __restrict__ Wn1,
                           const float* __restrict__ Wn2,
                           __bf16* __restrict__ We2p,
                           __bf16* __restrict__ Wx1p,
                           __bf16* __restrict__ Wn1p,
                           __bf16* __restrict__ Wn2p,
                           float4* __restrict__ co4,
                           int* __restrict__ cnt,           // pre-zeroed
                           __bf16* __restrict__ P1b,
                           __bf16* __restrict__ P2b)
{
    __shared__ __bf16 sC[64 * STR2];

    if (blockIdx.x < N_TILES) {
        // ---- pgemm tile: P1 = nf@We1[0:64]+be1, P2 = nf@We1[64:128] ----
        const int t    = threadIdx.x;
        const int lane = t & 63;
        const int w    = t >> 6;
        const int lr   = lane & 15;
        const int lk   = lane >> 4;
        const int n0   = blockIdx.x * 64;
        const int myrow = n0 + w * 16 + lr;
        const bool valid = (myrow < N_NODES);

        const bf16x8 zf = {(__bf16)0.f, (__bf16)0.f, (__bf16)0.f, (__bf16)0.f,
                           (__bf16)0.f, (__bf16)0.f, (__bf16)0.f, (__bf16)0.f};
        bf16x8 a0 = zf, a1 = zf;
        if (valid) {
            const float* np = node_feat + (size_t)myrow * 64;
            a0 = cvt8(*(const float4*)(np + lk * 8),      *(const float4*)(np + lk * 8 + 4));
            a1 = cvt8(*(const float4*)(np + 32 + lk * 8), *(const float4*)(np + 32 + lk * 8 + 4));
        }

        f32x4 acc[4];
#pragma unroll
        for (int pass = 0; pass < 2; ++pass) {
#pragma unroll
            for (int nt = 0; nt < 4; ++nt) {
                const int col = nt * 16 + lr;
                const float b0 = (pass == 0) ? be1[col] : 0.0f;
                acc[nt] = (f32x4){b0, b0, b0, b0};
                // transpose-on-load B fragments from f32 We1 (33KB table, L1-hot)
                const float* wp0 = We1 + (size_t)(pass * 64 + lk * 8) * 64 + col;
                const float* wp1 = wp0 + 32 * 64;
                bf16x8 b0f, b1f;
#pragma unroll
                for (int j = 0; j < 8; ++j) {
                    b0f[j] = (__bf16)wp0[j * 64];
                    b1f[j] = (__bf16)wp1[j * 64];
                }
                acc[nt] = __builtin_amdgcn_mfma_f32_16x16x32_bf16(a0, b0f, acc[nt], 0, 0, 0);
                acc[nt] = __builtin_amdgcn_mfma_f32_16x16x32_bf16(a1, b1f, acc[nt], 0, 0, 0);
            }
#pragma unroll
            for (int nt = 0; nt < 4; ++nt) {
                const int col = nt * 16 + lr;
#pragma unroll
                for (int r = 0; r < 4; ++r)
                    sC[(w * 16 + lk * 4 + r) * STR2 + col] = (__bf16)acc[nt][r];
            }
            if (valid) {
                __bf16* out = (pass == 0) ? P1b : P2b;
                bf16x8 v0 = *(const bf16x8*)&sC[(w * 16 + lr) * STR2 + lk * 8];
                bf16x8 v1 = *(const bf16x8*)&sC[(w * 16 + lr) * STR2 + 32 + lk * 8];
                *(bf16x8*)(out + (size_t)myrow * 64 + lk * 8)      = v0;
                *(bf16x8*)(out + (size_t)myrow * 64 + 32 + lk * 8) = v1;
            }
            __syncthreads();   // sC reuse between passes
        }
    } else {
        // ---- pack weights + co4 + histogram ----
        const int g = blockIdx.x - N_TILES;
        const int t = g * 256 + threadIdx.x;
        const int stride = (gridDim.x - N_TILES) * 256;    // 800000
        for (int i = t; i < 64 * 128; i += stride) {
            const int n = i >> 7, k = i & 127;
            Wn1p[i] = (__bf16)Wn1[k * 64 + n];
        }
        for (int i = t; i < 64 * 64; i += stride) {
            const int n = i >> 6, k = i & 63;
            We2p[i] = (__bf16)We2[k * 64 + n];
            Wx1p[i] = (__bf16)Wx1[k * 64 + n];
            Wn2p[i] = (__bf16)Wn2[k * 64 + n];
        }
        for (int n = t; n < N_NODES; n += stride)
            co4[n] = make_float4(coord[(size_t)n * 3], coord[(size_t)n * 3 + 1],
                                 coord[(size_t)n * 3 + 2], 0.0f);
        if (t < N_EDGES) atomicAdd(&cnt[dst[t]], 1);
    }
}

// ---------------- CSR scan: chunk scan then fused (bsum-scan + offsets) ----------------
__global__ void scan1_kernel(const int* __restrict__ cnt,
                             int* __restrict__ excl, int* __restrict__ bsum) {
    __shared__ int s[256];
    const int tid = threadIdx.x;
    const int i = blockIdx.x * 256 + tid;
    const int v = (i < N_NODES) ? cnt[i] : 0;
    s[tid] = v; __syncthreads();
#pragma unroll
    for (int off = 1; off < 256; off <<= 1) {
        int t = (tid >= off) ? s[tid - off] : 0;
        __syncthreads();
        s[tid] += t;
        __syncthreads();
    }
    if (i < N_NODES) excl[i] = s[tid] - v;
    if (tid == 255) bsum[blockIdx.x] = s[255];
}

__global__ void scan23_kernel(const int* __restrict__ bsum,
                              const int* __restrict__ excl,
                              int* __restrict__ offsets, int* __restrict__ cursor) {
    __shared__ int s[256];
    __shared__ int base;
    const int tid = threadIdx.x;
    const int bid = blockIdx.x;
    const int v = (tid < N_CHUNKS) ? bsum[tid] : 0;
    s[tid] = v; __syncthreads();
#pragma unroll
    for (int off = 1; off < 256; off <<= 1) {
        int t = (tid >= off) ? s[tid - off] : 0;
        __syncthreads();
        s[tid] += t;
        __syncthreads();
    }
    if (tid == 0) base = (bid > 0) ? s[bid - 1] : 0;
    __syncthreads();
    const int i = bid * 256 + tid;
    if (i < N_NODES) {
        const int o = base + excl[i];
        offsets[i] = o;
        cursor[i] = o;
    }
    if (bid == 0 && tid == 0) offsets[N_NODES] = N_EDGES;
}

__global__ void fill_v4(const int* __restrict__ src, const int* __restrict__ dst,
                        int* __restrict__ cursor,
                        int2* __restrict__ edge_p) {
    const int e = blockIdx.x * 256 + threadIdx.x;
    if (e < N_EDGES) {
        const int gs = src[e];
        const int gd = dst[e];
        const int p = atomicAdd(&cursor[gd], 1);
        edge_p[p] = make_int2(gs, gd);
    }
}

// ---------------- edge kernel v10: 2 edges/lane-row ILP + full occupancy ----------------
__global__ __launch_bounds__(256, 8)
void egnn_edge_mfma_v10(const __bf16* __restrict__ P1b,
                        const __bf16* __restrict__ P2b,
                        const int2* __restrict__ edge_p,
                        const float4* __restrict__ co4,
                        const float* __restrict__ We1,   // row 128 (radial) f32
                        const float* __restrict__ be2,
                        const float* __restrict__ bx1,
                        const float* __restrict__ Wx2,
                        const __bf16* __restrict__ We2p,
                        const __bf16* __restrict__ Wx1p,
                        float* __restrict__ h_neigh,     // [N*64] f32 accum
                        float* __restrict__ xs)          // [N*4]  f32 accum
{
    // wave-private LDS only (wave w owns rows w*32 .. w*32+31)
    __shared__ __bf16 sM[128 * STR2];
    __shared__ float  sCoef[128];

    const int t     = threadIdx.x;
    const int lane  = t & 63;
    const int w     = t >> 6;
    const int lr    = lane & 15;
    const int lk    = lane >> 4;
    const int j0    = blockIdx.x * 128;    // E = 6250*128, no tail
    const int rbase = w * 32;

    const int2 e0 = edge_p[j0 + rbase + lr];
    const int2 e1 = edge_p[j0 + rbase + 16 + lr];

    // ---- issue all scattered loads up front (two independent chains) ----
    const float4 cs0 = co4[e0.x], cd0 = co4[e0.y];
    const float4 cs1 = co4[e1.x], cd1 = co4[e1.y];
    const bf16x8 p1a0 = *(const bf16x8*)(P1b + (size_t)e0.x * 64 + lk * 8);
    const bf16x8 p1c0 = *(const bf16x8*)(P1b + (size_t)e0.x * 64 + 32 + lk * 8);
    const bf16x8 p2a0 = *(const bf16x8*)(P2b + (size_t)e0.y * 64 + lk * 8);
    const bf16x8 p2c0 = *(const bf16x8*)(P2b + (size_t)e0.y * 64 + 32 + lk * 8);
    const bf16x8 p1a1 = *(const bf16x8*)(P1b + (size_t)e1.x * 64 + lk * 8);
    const bf16x8 p1c1 = *(const bf16x8*)(P1b + (size_t)e1.x * 64 + 32 + lk * 8);
    const bf16x8 p2a1 = *(const bf16x8*)(P2b + (size_t)e1.y * 64 + lk * 8);
    const bf16x8 p2c1 = *(const bf16x8*)(P2b + (size_t)e1.y * 64 + 32 + lk * 8);

    // radial weight row (f32), this lane's column chunks
    const float4 w00 = *(const float4*)(We1 + 128 * 64 + lk * 8);
    const float4 w01 = *(const float4*)(We1 + 128 * 64 + lk * 8 + 4);
    const float4 w10 = *(const float4*)(We1 + 128 * 64 + 32 + lk * 8);
    const float4 w11 = *(const float4*)(We1 + 128 * 64 + 32 + lk * 8 + 4);
    const float wv0[8] = {w00.x, w00.y, w00.z, w00.w, w01.x, w01.y, w01.z, w01.w};
    const float wv1[8] = {w10.x, w10.y, w10.z, w10.w, w11.x, w11.y, w11.z, w11.w};

    // geometry
    const float dx0 = cs0.x - cd0.x, dy0 = cs0.y - cd0.y, dz0 = cs0.z - cd0.z;
    const float rad0 = dx0 * dx0 + dy0 * dy0 + dz0 * dz0;
    const float gi0 = fast_rcp(sqrtf(rad0) + EPS_F);
    const float gx0 = dx0 * gi0, gy0 = dy0 * gi0, gz0 = dz0 * gi0;
    const float dx1 = cs1.x - cd1.x, dy1 = cs1.y - cd1.y, dz1 = cs1.z - cd1.z;
    const float rad1 = dx1 * dx1 + dy1 * dy1 + dz1 * dz1;
    const float gi1 = fast_rcp(sqrtf(rad1) + EPS_F);
    const float gx1 = dx1 * gi1, gy1 = dy1 * gi1, gz1 = dz1 * gi1;

    f32x4 acc[4];

    // ================= group 0 =================
    {
        bf16x8 a0, a1;
#pragma unroll
        for (int u = 0; u < 8; ++u) {
            a0[u] = (__bf16)silu_f((float)p1a0[u] + (float)p2a0[u] + rad0 * wv0[u]);
            a1[u] = (__bf16)silu_f((float)p1c0[u] + (float)p2c0[u] + rad0 * wv1[u]);
        }
#pragma unroll
        for (int nt = 0; nt < 4; ++nt) {
            const float b0 = be2[nt * 16 + lr];
            acc[nt] = (f32x4){b0, b0, b0, b0};
            const __bf16* bp = We2p + (size_t)(nt * 16 + lr) * 64 + lk * 8;
            acc[nt] = __builtin_amdgcn_mfma_f32_16x16x32_bf16(a0, *(const bf16x8*)(bp),      acc[nt], 0, 0, 0);
            acc[nt] = __builtin_amdgcn_mfma_f32_16x16x32_bf16(a1, *(const bf16x8*)(bp + 32), acc[nt], 0, 0, 0);
        }
#pragma unroll
        for (int nt = 0; nt < 4; ++nt) {
            const int col = nt * 16 + lr;
#pragma unroll
            for (int r = 0; r < 4; ++r)
                sM[(rbase + lk * 4 + r) * STR2 + col] = (__bf16)silu_f(acc[nt][r]);
        }
        // layer 3 (coef)
        const bf16x8 m0 = *(const bf16x8*)&sM[(rbase + lr) * STR2 + lk * 8];
        const bf16x8 m1 = *(const bf16x8*)&sM[(rbase + lr) * STR2 + 32 + lk * 8];
#pragma unroll
        for (int nt = 0; nt < 4; ++nt) {
            const float b0 = bx1[nt * 16 + lr];
            acc[nt] = (f32x4){b0, b0, b0, b0};
            const __bf16* bp = Wx1p + (size_t)(nt * 16 + lr) * 64 + lk * 8;
            acc[nt] = __builtin_amdgcn_mfma_f32_16x16x32_bf16(m0, *(const bf16x8*)(bp),      acc[nt], 0, 0, 0);
            acc[nt] = __builtin_amdgcn_mfma_f32_16x16x32_bf16(m1, *(const bf16x8*)(bp + 32), acc[nt], 0, 0, 0);
        }
        float p[4] = {0.f, 0.f, 0.f, 0.f};
#pragma unroll
        for (int nt = 0; nt < 4; ++nt) {
            const float wv = Wx2[nt * 16 + lr];
#pragma unroll
            for (int r = 0; r < 4; ++r)
                p[r] += silu_f(acc[nt][r]) * wv;
        }
#pragma unroll
        for (int off = 1; off < 16; off <<= 1)
#pragma unroll
            for (int r = 0; r < 4; ++r)
                p[r] += __shfl_xor(p[r], off);
        if (lr == 0) {
#pragma unroll
            for (int r = 0; r < 4; ++r)
                sCoef[rbase + lk * 4 + r] = p[r];
        }
    }

    // ================= group 1 =================
    {
        bf16x8 a0, a1;
#pragma unroll
        for (int u = 0; u < 8; ++u) {
            a0[u] = (__bf16)silu_f((float)p1a1[u] + (float)p2a1[u] + rad1 * wv0[u]);
            a1[u] = (__bf16)silu_f((float)p1c1[u] + (float)p2c1[u] + rad1 * wv1[u]);
        }
#pragma unroll
        for (int nt = 0; nt < 4; ++nt) {
            const float b0 = be2[nt * 16 + lr];
            acc[nt] = (f32x4){b0, b0, b0, b0};
            const __bf16* bp = We2p + (size_t)(nt * 16 + lr) * 64 + lk * 8;
            acc[nt] = __builtin_amdgcn_mfma_f32_16x16x32_bf16(a0, *(const bf16x8*)(bp),      acc[nt], 0, 0, 0);
            acc[nt] = __builtin_amdgcn_mfma_f32_16x16x32_bf16(a1, *(const bf16x8*)(bp + 32), acc[nt], 0, 0, 0);
        }
#pragma unroll
        for (int nt = 0; nt < 4; ++nt) {
            const int col = nt * 16 + lr;
#pragma unroll
            for (int r = 0; r < 4; ++r)
                sM[(rbase + 16 + lk * 4 + r) * STR2 + col] = (__bf16)silu_f(acc[nt][r]);
        }
        // layer 3 (coef)
        const bf16x8 m0 = *(const bf16x8*)&sM[(rbase + 16 + lr) * STR2 + lk * 8];
        const bf16x8 m1 = *(const bf16x8*)&sM[(rbase + 16 + lr) * STR2 + 32 + lk * 8];
#pragma unroll
        for (int nt = 0; nt < 4; ++nt) {
            const float b0 = bx1[nt * 16 + lr];
            acc[nt] = (f32x4){b0, b0, b0, b0};
            const __bf16* bp = Wx1p + (size_t)(nt * 16 + lr) * 64 + lk * 8;
            acc[nt] = __builtin_amdgcn_mfma_f32_16x16x32_bf16(m0, *(const bf16x8*)(bp),      acc[nt], 0, 0, 0);
            acc[nt] = __builtin_amdgcn_mfma_f32_16x16x32_bf16(m1, *(const bf16x8*)(bp + 32), acc[nt], 0, 0, 0);
        }
        float p[4] = {0.f, 0.f, 0.f, 0.f};
#pragma unroll
        for (int nt = 0; nt < 4; ++nt) {
            const float wv = Wx2[nt * 16 + lr];
#pragma unroll
            for (int r = 0; r < 4; ++r)
                p[r] += silu_f(acc[nt][r]) * wv;
        }
#pragma unroll
        for (int off = 1; off < 16; off <<= 1)
#pragma unroll
            for (int r = 0; r < 4; ++r)
                p[r] += __shfl_xor(p[r], off);
        if (lr == 0) {
#pragma unroll
            for (int r = 0; r < 4; ++r)
                sCoef[rbase + 16 + lk * 4 + r] = p[r];
        }
    }

    // ---- column segment-reduce of 32 msg rows onto h_neigh ----
    {
        float accum = 0.0f;
        int cur = __shfl(e0.y, 0);
#pragma unroll
        for (int rr = 0; rr < 32; ++rr) {
            const int d = (rr < 16) ? __shfl(e0.y, rr) : __shfl(e1.y, rr - 16);
            const float v = (float)sM[(rbase + rr) * STR2 + lane];
            if (d != cur) {                   // wave-uniform branch
                atomicAdd(&h_neigh[(size_t)cur * 64 + lane], accum);
                accum = 0.0f; cur = d;
            }
            accum += v;
        }
        atomicAdd(&h_neigh[(size_t)cur * 64 + lane], accum);
    }

    // ---- xs: in-wave segmented shuffle-reduce, group 0 then group 1 ----
    {
        const float c = sCoef[rbase + lr];
        float vx = c * gx0, vy = c * gy0, vz = c * gz0;
        const int d = e0.y;
#pragma unroll
        for (int off = 1; off < 16; off <<= 1) {
            const int   od = __shfl(d,  lane + off);
            const float ox = __shfl(vx, lane + off);
            const float oy = __shfl(vy, lane + off);
            const float oz = __shfl(vz, lane + off);
            if ((lr + off < 16) && (od == d)) { vx += ox; vy += oy; vz += oz; }
        }
        const int pd = __shfl(d, lane - 1);
        const bool head = (lr == 0) || (pd != d);
        if (head && lk == 0) {
            atomicAdd(&xs[(size_t)d * 4 + 0], vx);
            atomicAdd(&xs[(size_t)d * 4 + 1], vy);
            atomicAdd(&xs[(size_t)d * 4 + 2], vz);
        }
    }
    {
        const float c = sCoef[rbase + 16 + lr];
        float vx = c * gx1, vy = c * gy1, vz = c * gz1;
        const int d = e1.y;
#pragma unroll
        for (int off = 1; off < 16; off <<= 1) {
            const int   od = __shfl(d,  lane + off);
            const float ox = __shfl(vx, lane + off);
            const float oy = __shfl(vy, lane + off);
            const float oz = __shfl(vz, lane + off);
            if ((lr + off < 16) && (od == d)) { vx += ox; vy += oy; vz += oz; }
        }
        const int pd = __shfl(d, lane - 1);
        const bool head = (lr == 0) || (pd != d);
        if (head && lk == 0) {
            atomicAdd(&xs[(size_t)d * 4 + 0], vx);
            atomicAdd(&xs[(size_t)d * 4 + 1], vy);
            atomicAdd(&xs[(size_t)d * 4 + 2], vz);
        }
    }
}

// ---------------- node kernel v6: f32 reads, reg A-fragments ----------------
__global__ __launch_bounds__(256, 8)
void egnn_node_mfma_v6(const float* __restrict__ node_feat,
                       const float* __restrict__ coord,
                       const int* __restrict__ offsets,
                       const float* __restrict__ h_neigh,   // [N*64] f32
                       const float4* __restrict__ xs,       // [N]
                       const float* __restrict__ bn1,
                       const float* __restrict__ bn2,
                       const __bf16* __restrict__ Wn1p,
                       const __bf16* __restrict__ Wn2p,
                       float* __restrict__ out_h,
                       float* __restrict__ out_x)
{
    __shared__ __bf16 sT[64 * STR2];   // wave-private slices

    const int t    = threadIdx.x;
    const int lane = t & 63;
    const int w    = t >> 6;
    const int lr   = lane & 15;
    const int lk   = lane >> 4;
    const int n0   = blockIdx.x * 64;
    const int myrow = n0 + w * 16 + lr;
    const bool valid = (myrow < N_NODES);

    const bf16x8 zf = {(__bf16)0.f, (__bf16)0.f, (__bf16)0.f, (__bf16)0.f,
                       (__bf16)0.f, (__bf16)0.f, (__bf16)0.f, (__bf16)0.f};

    bf16x8 a0 = zf, a1 = zf, a2 = zf, a3 = zf;
    if (valid) {
        const float* np = node_feat + (size_t)myrow * 64;
        a0 = cvt8(*(const float4*)(np + lk * 8),      *(const float4*)(np + lk * 8 + 4));
        a1 = cvt8(*(const float4*)(np + 32 + lk * 8), *(const float4*)(np + 32 + lk * 8 + 4));
        const float* hp = h_neigh + (size_t)myrow * 64;
        a2 = cvt8(*(const float4*)(hp + lk * 8),      *(const float4*)(hp + lk * 8 + 4));
        a3 = cvt8(*(const float4*)(hp + 32 + lk * 8), *(const float4*)(hp + 32 + lk * 8 + 4));
    }

    // coordinate update (first wave, one thread per node)
    if (t < 64) {
        const int n = n0 + t;
        if (n < N_NODES) {
            const int deg = offsets[n + 1] - offsets[n];
            const float inv = fast_rcp(fmaxf((float)deg, 1.0f));
            const float4 xv = xs[n];
            out_x[(size_t)n * 3 + 0] = coord[(size_t)n * 3 + 0] + xv.x * inv;
            out_x[(size_t)n * 3 + 1] = coord[(size_t)n * 3 + 1] + xv.y * inv;
            out_x[(size_t)n * 3 + 2] = coord[(size_t)n * 3 + 2] + xv.z * inv;
        }
    }

    f32x4 acc[4];

    // ---- node layer 1 (K=128) ----
#pragma unroll
    for (int nt = 0; nt < 4; ++nt) {
        const float b0 = bn1[nt * 16 + lr];
        acc[nt] = (f32x4){b0, b0, b0, b0};
        const __bf16* bp = Wn1p + (size_t)(nt * 16 + lr) * 128 + lk * 8;
        acc[nt] = __builtin_amdgcn_mfma_f32_16x16x32_bf16(a0, *(const bf16x8*)(bp),      acc[nt], 0, 0, 0);
        acc[nt] = __builtin_amdgcn_mfma_f32_16x16x32_bf16(a1, *(const bf16x8*)(bp + 32), acc[nt], 0, 0, 0);
        acc[nt] = __builtin_amdgcn_mfma_f32_16x16x32_bf16(a2, *(const bf16x8*)(bp + 64), acc[nt], 0, 0, 0);
        acc[nt] = __builtin_amdgcn_mfma_f32_16x16x32_bf16(a3, *(const bf16x8*)(bp + 96), acc[nt], 0, 0, 0);
    }
#pragma unroll
    for (int nt = 0; nt < 4; ++nt) {
        const int col = nt * 16 + lr;
#pragma unroll
        for (int rr = 0; rr < 4; ++rr)
            sT[(w * 16 + lk * 4 + rr) * STR2 + col] = (__bf16)silu_f(acc[nt][rr]);
    }

    // ---- node layer 2 (K=64), direct stores ----
    {
        const bf16x8 b0f = *(const bf16x8*)&sT[(w * 16 + lr) * STR2 + lk * 8];
        const bf16x8 b1f = *(const bf16x8*)&sT[(w * 16 + lr) * STR2 + 32 + lk * 8];
#pragma unroll
        for (int nt = 0; nt < 4; ++nt) {
            const float b0 = bn2[nt * 16 + lr];
            acc[nt] = (f32x4){b0, b0, b0, b0};
            const __bf16* bp = Wn2p + (size_t)(nt * 16 + lr) * 64 + lk * 8;
            acc[nt] = __builtin_amdgcn_mfma_f32_16x16x32_bf16(b0f, *(const bf16x8*)(bp),      acc[nt], 0, 0, 0);
            acc[nt] = __builtin_amdgcn_mfma_f32_16x16x32_bf16(b1f, *(const bf16x8*)(bp + 32), acc[nt], 0, 0, 0);
        }
#pragma unroll
        for (int nt = 0; nt < 4; ++nt) {
            const int col = nt * 16 + lr;
#pragma unroll
            for (int rr = 0; rr < 4; ++rr) {
                const int row = n0 + w * 16 + lk * 4 + rr;
                if (row < N_NODES)
                    out_h[(size_t)row * 64 + col] = acc[nt][rr];
            }
        }
    }
}

// ================= fallback path (atomics) =================
__global__ void prep_kernel(const float* __restrict__ node_feat,
                            const float* __restrict__ We1,
                            const float* __restrict__ We2,
                            const float* __restrict__ Wx1,
                            const float* __restrict__ Wn1,
                            const float* __restrict__ Wn2,
                            __bf16* __restrict__ nfb,
                            __bf16* __restrict__ We1p,
                            __bf16* __restrict__ We2p,
                            __bf16* __restrict__ Wx1p,
                            __bf16* __restrict__ Wn1p,
                            __bf16* __restrict__ Wn2p)
{
    const int t = blockIdx.x * 256 + threadIdx.x;
    const int stride = gridDim.x * 256;
    for (int i = t; i < N_NODES * 64; i += stride)
        nfb[i] = (__bf16)node_feat[i];
    for (int i = t; i < 64 * 128; i += stride) {
        const int n = i >> 7, k = i & 127;
        We1p[i] = (__bf16)We1[k * 64 + n];
        Wn1p[i] = (__bf16)Wn1[k * 64 + n];
    }
    for (int i = t; i < 64 * 64; i += stride) {
        const int n = i >> 6, k = i & 63;
        We2p[i] = (__bf16)We2[k * 64 + n];
        Wx1p[i] = (__bf16)Wx1[k * 64 + n];
        Wn2p[i] = (__bf16)Wn2[k * 64 + n];
    }
}

__global__ __launch_bounds__(256, 4)
void egnn_edge_mfma_atomic(const float* __restrict__ node_feat,
                           const float* __restrict__ coord,
                           const int* __restrict__ src,
                           const int* __restrict__ dst,
                           const float* __restrict__ We1,
                           const float* __restrict__ be1,
                           const float* __restrict__ be2,
                           const float* __restrict__ bx1,
                           const float* __restrict__ Wx2,
                           const __bf16* __restrict__ We1p,
                           const __bf16* __restrict__ We2p,
                           const __bf16* __restrict__ Wx1p,
                           float* __restrict__ h_neigh,
                           float* __restrict__ x_sum,
                           float* __restrict__ deg)
{
    __shared__ __bf16 sFb[64 * STR1];
    __shared__ __bf16 sT [64 * STR2];
    __shared__ __bf16 sM [64 * STR2];
    __shared__ float  sRad[64];
    __shared__ float  sXd[64][3];
    __shared__ int    sDst[64];

    const int t  = threadIdx.x;
    const int e0 = blockIdx.x * 64;

    {
        const int e = t >> 2, sub = t & 3;
        const int gs = src[e0 + e];
        const int gd = dst[e0 + e];
        const float4* rs = (const float4*)(node_feat + (size_t)gs * 64) + sub * 4;
        const float4* rd = (const float4*)(node_feat + (size_t)gd * 64) + sub * 4;
#pragma unroll
        for (int q = 0; q < 4; ++q) {
            float4 a = rs[q];
            float4 b = rd[q];
            *(bf16x4*)&sFb[e * STR1 + sub * 16 + 4 * q] =
                (bf16x4){(__bf16)a.x, (__bf16)a.y, (__bf16)a.z, (__bf16)a.w};
            *(bf16x4*)&sFb[e * STR1 + 64 + sub * 16 + 4 * q] =
                (bf16x4){(__bf16)b.x, (__bf16)b.y, (__bf16)b.z, (__bf16)b.w};
        }
    }
    if (t < 64) {
        const int e  = t;
        const int gs = src[e0 + e];
        const int gd = dst[e0 + e];
        float dx = coord[(size_t)gs * 3 + 0] - coord[(size_t)gd * 3 + 0];
        float dy = coord[(size_t)gs * 3 + 1] - coord[(size_t)gd * 3 + 1];
        float dz = coord[(size_t)gs * 3 + 2] - coord[(size_t)gd * 3 + 2];
        float radial = dx * dx + dy * dy + dz * dz;
        sRad[e] = radial;
        float inv = fast_rcp(sqrtf(radial) + EPS_F);
        sXd[e][0] = dx * inv; sXd[e][1] = dy * inv; sXd[e][2] = dz * inv;
        sDst[e] = gd;
    }
    __syncthreads();

    const int lane = t & 63;
    const int w    = t >> 6;
    const int lr   = lane & 15;
    const int lk   = lane >> 4;

    f32x4 acc[4];
    {
#pragma unroll
        for (int nt = 0; nt < 4; ++nt) {
            const int col = nt * 16 + lr;
            const float b0 = be1[col];
            const float wr = We1[128 * 64 + col];
#pragma unroll
            for (int r = 0; r < 4; ++r)
                acc[nt][r] = b0 + sRad[w * 16 + lk * 4 + r] * wr;
        }
        const int arow = w * 16 + lr;
#pragma unroll
        for (int ks = 0; ks < 4; ++ks) {
            bf16x8 a = *(const bf16x8*)&sFb[arow * STR1 + ks * 32 + lk * 8];
#pragma unroll
            for (int nt = 0; nt < 4; ++nt) {
                bf16x8 b = *(const bf16x8*)&We1p[(nt * 16 + lr) * 128 + ks * 32 + lk * 8];
                acc[nt] = __builtin_amdgcn_mfma_f32_16x16x32_bf16(a, b, acc[nt], 0, 0, 0);
            }
        }
#pragma unroll
        for (int nt = 0; nt < 4; ++nt) {
            const int col = nt * 16 + lr;
#pragma unroll
            for (int r = 0; r < 4; ++r) {
                const int row = w * 16 + lk * 4 + r;
                sT[row * STR2 + col] = (__bf16)silu_f(acc[nt][r]);
            }
        }
    }
    __syncthreads();
    {
#pragma unroll
        for (int nt = 0; nt < 4; ++nt) {
            const float b0 = be2[nt * 16 + lr];
            acc[nt] = (f32x4){b0, b0, b0, b0};
        }
        const int arow = w * 16 + lr;
#pragma unroll
        for (int ks = 0; ks < 2; ++ks) {
            bf16x8 a = *(const bf16x8*)&sT[arow * STR2 + ks * 32 + lk * 8];
#pragma unroll
            for (int nt = 0; nt < 4; ++nt) {
                bf16x8 b = *(const bf16x8*)&We2p[(nt * 16 + lr) * 64 + ks * 32 + lk * 8];
                acc[nt] = __builtin_amdgcn_mfma_f32_16x16x32_bf16(a, b, acc[nt], 0, 0, 0);
            }
        }
#pragma unroll
        for (int nt = 0; nt < 4; ++nt) {
            const int col = nt * 16 + lr;
#pragma unroll
            for (int r = 0; r < 4; ++r) {
                const int row = w * 16 + lk * 4 + r;
                const float v = silu_f(acc[nt][r]);
                sM[row * STR2 + col] = (__bf16)v;
                atomicAdd(&h_neigh[(size_t)sDst[row] * 64 + col], v);
            }
        }
    }
    __syncthreads();
    {
#pragma unroll
        for (int nt = 0; nt < 4; ++nt) {
            const float b0 = bx1[nt * 16 + lr];
            acc[nt] = (f32x4){b0, b0, b0, b0};
        }
        const int arow = w * 16 + lr;
#pragma unroll
        for (int ks = 0; ks < 2; ++ks) {
            bf16x8 a = *(const bf16x8*)&sM[arow * STR2 + ks * 32 + lk * 8];
#pragma unroll
            for (int nt = 0; nt < 4; ++nt) {
                bf16x8 b = *(const bf16x8*)&Wx1p[(nt * 16 + lr) * 64 + ks * 32 + lk * 8];
                acc[nt] = __builtin_amdgcn_mfma_f32_16x16x32_bf16(a, b, acc[nt], 0, 0, 0);
            }
        }
        float p[4] = {0.f, 0.f, 0.f, 0.f};
#pragma unroll
        for (int nt = 0; nt < 4; ++nt) {
            const float wv = Wx2[nt * 16 + lr];
#pragma unroll
            for (int r = 0; r < 4; ++r)
                p[r] += silu_f(acc[nt][r]) * wv;
        }
#pragma unroll
        for (int off = 1; off < 16; off <<= 1)
#pragma unroll
            for (int r = 0; r < 4; ++r)
                p[r] += __shfl_xor(p[r], off);
        if (lr == 0) {
#pragma unroll
            for (int r = 0; r < 4; ++r) {
                const int e  = w * 16 + lk * 4 + r;
                const int gd = sDst[e];
                const float coef = p[r];
                atomicAdd(&x_sum[(size_t)gd * 3 + 0], coef * sXd[e][0]);
                atomicAdd(&x_sum[(size_t)gd * 3 + 1], coef * sXd[e][1]);
                atomicAdd(&x_sum[(size_t)gd * 3 + 2], coef * sXd[e][2]);
                atomicAdd(&deg[gd], 1.0f);
            }
        }
    }
}

template<int KDIM>
__device__ __forceinline__ void tile_gemm64(const float* __restrict__ A, int astride,
                                            const float* __restrict__ B,
                                            float acc[4][4], int t)
{
    const int tx = t & 15;
    const int ty = t >> 4;
#pragma unroll
    for (int i = 0; i < 4; ++i)
#pragma unroll
        for (int j = 0; j < 4; ++j) acc[i][j] = 0.0f;

    for (int k = 0; k < KDIM; k += 4) {
        float bv[4][4];
#pragma unroll
        for (int kk = 0; kk < 4; ++kk) {
            float4 bq = *(const float4*)(B + (size_t)(k + kk) * 64 + tx * 4);
            bv[kk][0] = bq.x; bv[kk][1] = bq.y; bv[kk][2] = bq.z; bv[kk][3] = bq.w;
        }
#pragma unroll
        for (int i = 0; i < 4; ++i) {
            float4 aq = *(const float4*)(A + (size_t)(ty * 4 + i) * astride + k);
            float av[4] = {aq.x, aq.y, aq.z, aq.w};
#pragma unroll
            for (int kk = 0; kk < 4; ++kk)
#pragma unroll
                for (int j = 0; j < 4; ++j)
                    acc[i][j] = fmaf(av[kk], bv[kk][j], acc[i][j]);
        }
    }
}

__global__ __launch_bounds__(256, 2)
void egnn_node_kernel(const float* __restrict__ node_feat,
                      const float* __restrict__ coord,
                      const float* __restrict__ Wn1, const float* __restrict__ bn1,
                      const float* __restrict__ Wn2, const float* __restrict__ bn2,
                      const float* __restrict__ h_neigh,
                      const float* __restrict__ x_sum,
                      const float* __restrict__ deg,
                      float* __restrict__ out_h,
                      float* __restrict__ out_x)
{
    __shared__ float sF[64][132];
    __shared__ float sT2[64][68];

    const int t  = threadIdx.x;
    const int n0 = blockIdx.x * 64;

    {
        const int r = t >> 2;
        const int sub = t & 3;
        const int n = n0 + r;
        if (n < N_NODES) {
            const float* rowsrc = (sub < 2) ? (node_feat + (size_t)n * 64 + sub * 32)
                                            : (h_neigh  + (size_t)n * 64 + (sub - 2) * 32);
#pragma unroll
            for (int q = 0; q < 8; ++q)
                *(float4*)&sF[r][sub * 32 + 4 * q] = *(const float4*)(rowsrc + 4 * q);
        } else {
#pragma unroll
            for (int q = 0; q < 8; ++q)
                *(float4*)&sF[r][sub * 32 + 4 * q] = make_float4(0.f, 0.f, 0.f, 0.f);
        }
    }
    __syncthreads();

    const int tx = t & 15;
    const int ty = t >> 4;
    float acc[4][4];

    tile_gemm64<128>(&sF[0][0], 132, Wn1, acc, t);
    {
        float4 bq = *(const float4*)(bn1 + tx * 4);
        float bv[4] = {bq.x, bq.y, bq.z, bq.w};
#pragma unroll
        for (int i = 0; i < 4; ++i) {
            float4 o;
            o.x = silu_f(acc[i][0] + bv[0]);
            o.y = silu_f(acc[i][1] + bv[1]);
            o.z = silu_f(acc[i][2] + bv[2]);
            o.w = silu_f(acc[i][3] + bv[3]);
            *(float4*)&sT2[ty * 4 + i][tx * 4] = o;
        }
    }
    __syncthreads();

    tile_gemm64<64>(&sT2[0][0], 68, Wn2, acc, t);
    {
        float4 bq = *(const float4*)(bn2 + tx * 4);
        float bv[4] = {bq.x, bq.y, bq.z, bq.w};
#pragma unroll
        for (int i = 0; i < 4; ++i) {
            const int n = n0 + ty * 4 + i;
            if (n < N_NODES) {
                float4 o;
                o.x = acc[i][0] + bv[0];
                o.y = acc[i][1] + bv[1];
                o.z = acc[i][2] + bv[2];
                o.w = acc[i][3] + bv[3];
                *(float4*)&out_h[(size_t)n * 64 + tx * 4] = o;
            }
        }
    }

    if (t < 64) {
        const int n = n0 + t;
        if (n < N_NODES) {
            const float d = deg[n];
            const float inv = fast_rcp(fmaxf(d, 1.0f));
#pragma unroll
            for (int c = 0; c < 3; ++c)
                out_x[(size_t)n * 3 + c] = coord[(size_t)n * 3 + c]
                                         + x_sum[(size_t)n * 3 + c] * inv;
        }
    }
}

// ================= host =================
extern "C" void kernel_launch(void* const* d_in, const int* in_sizes, int n_in,
                              void* d_out, int out_size, void* d_ws, size_t ws_size,
                              hipStream_t stream) {
    const float* node_feat = (const float*)d_in[0];
    const float* coord     = (const float*)d_in[1];
    const int*   src       = (const int*)d_in[2];
    const int*   dst       = (const int*)d_in[3];
    const float* We1 = (const float*)d_in[4];
    const float* be1 = (const float*)d_in[5];
    const float* We2 = (const float*)d_in[6];
    const float* be2 = (const float*)d_in[7];
    const float* Wx1 = (const float*)d_in[8];
    const float* bx1 = (const float*)d_in[9];
    const float* Wx2 = (const float*)d_in[10];
    const float* Wn1 = (const float*)d_in[11];
    const float* bn1 = (const float*)d_in[12];
    const float* Wn2 = (const float*)d_in[13];
    const float* bn2 = (const float*)d_in[14];

    float* out_h = (float*)d_out;
    float* out_x = out_h + (size_t)N_NODES * 64;

    // ---- workspace layout (fast path); h_neigh/xs/cnt contiguous for ONE memset ----
    char* ws = (char*)d_ws;
    size_t off = 0;
    auto take = [&](size_t bytes) { char* p = ws + off; off = (off + bytes + 255) & ~(size_t)255; return p; };

    float*  h_neigh = (float*)take((size_t)N_NODES * 64 * 4);   // 12.8MB
    float*  xs      = (float*)take((size_t)N_NODES * 16);       // 800KB
    int*    cnt     = (int*)take((size_t)N_NODES * 4);          // 200KB
    const size_t zero_span = off;                                // one memset covers all
    int2*   edge_p  = (int2*)take((size_t)N_EDGES * 8);
    float4* co4     = (float4*)take((size_t)N_NODES * 16);
    __bf16* P1b     = (__bf16*)take((size_t)N_NODES * 64 * 2);
    __bf16* P2b     = (__bf16*)take((size_t)N_NODES * 64 * 2);
    int*    offsets = (int*)take((size_t)(N_NODES + 1) * 4);
    int*    cursor  = (int*)take((size_t)N_NODES * 4);
    int*    excl    = (int*)take((size_t)N_NODES * 4);
    int*    bsum    = (int*)take(1024);
    __bf16* We2p    = (__bf16*)take(64 * 64 * 2);
    __bf16* Wx1p    = (__bf16*)take(64 * 64 * 2);
    __bf16* Wn1p    = (__bf16*)take(64 * 128 * 2);
    __bf16* Wn2p    = (__bf16*)take(64 * 64 * 2);
    const size_t needed = off;

    if (ws_size >= needed) {
        hipMemsetAsync(d_ws, 0, zero_span, stream);

        // one fused launch: pgemm tiles (blocks 0..781) | pack+co4+histogram (rest)
        fused_prep<<<N_TILES + (N_EDGES + 255) / 256, 256, 0, stream>>>(
            node_feat, coord, dst,
            We1, be1, We2, Wx1, Wn1, Wn2,
            We2p, Wx1p, Wn1p, Wn2p, co4, cnt, P1b, P2b);

        scan1_kernel<<<N_CHUNKS, 256, 0, stream>>>(cnt, excl, bsum);
        scan23_kernel<<<N_CHUNKS, 256, 0, stream>>>(bsum, excl, offsets, cursor);
        fill_v4<<<(N_EDGES + 255) / 256, 256, 0, stream>>>(src, dst, cursor, edge_p);

        egnn_edge_mfma_v10<<<N_EDGES / 128, 256, 0, stream>>>(
            P1b, P2b, edge_p, co4,
            We1, be2, bx1, Wx2,
            We2p, Wx1p,
            h_neigh, xs);

        egnn_node_mfma_v6<<<(N_NODES + 63) / 64, 256, 0, stream>>>(
            node_feat, coord, offsets, h_neigh, (const float4*)xs,
            bn1, bn2, Wn1p, Wn2p, out_h, out_x);
    } else {
        // ======== fallback: atomic path ========
        float* fh_neigh = (float*)d_ws;
        float* fx_sum   = fh_neigh + (size_t)N_NODES * 64;
        float* fdeg     = fx_sum + (size_t)N_NODES * 3;
        __bf16* fnfb    = (__bf16*)(fdeg + N_NODES);
        __bf16* fWe1p   = fnfb + (size_t)N_NODES * 64;
        __bf16* fWe2p   = fWe1p + 64 * 128;
        __bf16* fWx1p   = fWe2p + 64 * 64;
        __bf16* fWn1p   = fWx1p + 64 * 64;
        __bf16* fWn2p   = fWn1p + 64 * 128;

        hipMemsetAsync(d_ws, 0, (size_t)N_NODES * 68 * sizeof(float), stream);
        prep_kernel<<<2048, 256, 0, stream>>>(node_feat, We1, We2, Wx1, Wn1, Wn2,
                                              fnfb, fWe1p, fWe2p, fWx1p, fWn1p, fWn2p);
        egnn_edge_mfma_atomic<<<N_EDGES / 64, 256, 0, stream>>>(
            node_feat, coord, src, dst,
            We1, be1, be2, bx1, Wx2,
            fWe1p, fWe2p, fWx1p,
            fh_neigh, fx_sum, fdeg);
        egnn_node_kernel<<<(N_NODES + 63) / 64, 256, 0, stream>>>(
            node_feat, coord, Wn1, bn1, Wn2, bn2,
            fh_neigh, fx_sum, fdeg, out_h, out_x);
    }
}

// Round 13
// 260.573 us; speedup vs baseline: 1.1211x; 1.1211x over previous
//
#include <hip/hip_runtime.h>
#include <math.h>

#define N_NODES 50000
#define N_EDGES 800000
#define EPS_F 1e-30f
#define N_TILES 782     // ceil(N_NODES/64)  (pgemm blocks)
#define N_CHUNKS 196    // ceil(N_NODES/256) (scan chunks)

typedef __bf16 bf16x8 __attribute__((ext_vector_type(8)));
typedef __bf16 bf16x4 __attribute__((ext_vector_type(4)));
typedef float  f32x4  __attribute__((ext_vector_type(4)));

#define STR1 136   // 128-wide bf16 tile row stride (fallback kernel)
#define STR2 72    // 64-wide bf16 tile row stride (144B)

// 1-ulp hardware reciprocal: avoids the IEEE div sequence (~10 VALU ops)
__device__ __forceinline__ float fast_rcp(float x) {
    float r;
    asm("v_rcp_f32 %0, %1" : "=v"(r) : "v"(x));
    return r;
}

__device__ __forceinline__ float silu_f(float x) {
    return x * fast_rcp(1.0f + __expf(-x));
}

__device__ __forceinline__ bf16x8 cvt8(float4 u0, float4 u1) {
    return (bf16x8){(__bf16)u0.x, (__bf16)u0.y, (__bf16)u0.z, (__bf16)u0.w,
                    (__bf16)u1.x, (__bf16)u1.y, (__bf16)u1.z, (__bf16)u1.w};
}

// ---------------- fused prologue: [pgemm tiles | weight pack + co4 + histogram] ----------------
__global__ void fused_prep(const float* __restrict__ node_feat,
                           const float* __restrict__ coord,
                           const int* __restrict__ dst,
                           const float* __restrict__ We1,   // [129][64] f32
                           const float* __restrict__ be1,
                           const float* __restrict__ We2,
                           const float* __restrict__ Wx1,
                           const float* __restrict__ Wn1,
                           const float* __restrict__ Wn2,
                           __bf16* __restrict__ We2p,
                           __bf16* __restrict__ Wx1p,
                           __bf16* __restrict__ Wn1p,
                           __bf16* __restrict__ Wn2p,
                           float4* __restrict__ co4,
                           int* __restrict__ cnt,           // pre-zeroed
                           __bf16* __restrict__ P1b,
                           __bf16* __restrict__ P2b)
{
    __shared__ __bf16 sC[64 * STR2];

    if (blockIdx.x < N_TILES) {
        // ---- pgemm tile: P1 = nf@We1[0:64]+be1, P2 = nf@We1[64:128] ----
        const int t    = threadIdx.x;
        const int lane = t & 63;
        const int w    = t >> 6;
        const int lr   = lane & 15;
        const int lk   = lane >> 4;
        const int n0   = blockIdx.x * 64;
        const int myrow = n0 + w * 16 + lr;
        const bool valid = (myrow < N_NODES);

        const bf16x8 zf = {(__bf16)0.f, (__bf16)0.f, (__bf16)0.f, (__bf16)0.f,
                           (__bf16)0.f, (__bf16)0.f, (__bf16)0.f, (__bf16)0.f};
        bf16x8 a0 = zf, a1 = zf;
        if (valid) {
            const float* np = node_feat + (size_t)myrow * 64;
            a0 = cvt8(*(const float4*)(np + lk * 8),      *(const float4*)(np + lk * 8 + 4));
            a1 = cvt8(*(const float4*)(np + 32 + lk * 8), *(const float4*)(np + 32 + lk * 8 + 4));
        }

        f32x4 acc[4];
#pragma unroll
        for (int pass = 0; pass < 2; ++pass) {
#pragma unroll
            for (int nt = 0; nt < 4; ++nt) {
                const int col = nt * 16 + lr;
                const float b0 = (pass == 0) ? be1[col] : 0.0f;
                acc[nt] = (f32x4){b0, b0, b0, b0};
                // transpose-on-load B fragments from f32 We1 (33KB table, L1-hot)
                const float* wp0 = We1 + (size_t)(pass * 64 + lk * 8) * 64 + col;
                const float* wp1 = wp0 + 32 * 64;
                bf16x8 b0f, b1f;
#pragma unroll
                for (int j = 0; j < 8; ++j) {
                    b0f[j] = (__bf16)wp0[j * 64];
                    b1f[j] = (__bf16)wp1[j * 64];
                }
                acc[nt] = __builtin_amdgcn_mfma_f32_16x16x32_bf16(a0, b0f, acc[nt], 0, 0, 0);
                acc[nt] = __builtin_amdgcn_mfma_f32_16x16x32_bf16(a1, b1f, acc[nt], 0, 0, 0);
            }
#pragma unroll
            for (int nt = 0; nt < 4; ++nt) {
                const int col = nt * 16 + lr;
#pragma unroll
                for (int r = 0; r < 4; ++r)
                    sC[(w * 16 + lk * 4 + r) * STR2 + col] = (__bf16)acc[nt][r];
            }
            if (valid) {
                __bf16* out = (pass == 0) ? P1b : P2b;
                bf16x8 v0 = *(const bf16x8*)&sC[(w * 16 + lr) * STR2 + lk * 8];
                bf16x8 v1 = *(const bf16x8*)&sC[(w * 16 + lr) * STR2 + 32 + lk * 8];
                *(bf16x8*)(out + (size_t)myrow * 64 + lk * 8)      = v0;
                *(bf16x8*)(out + (size_t)myrow * 64 + 32 + lk * 8) = v1;
            }
            __syncthreads();   // sC reuse between passes
        }
    } else {
        // ---- pack weights + co4 + histogram ----
        const int g = blockIdx.x - N_TILES;
        const int t = g * 256 + threadIdx.x;
        const int stride = (gridDim.x - N_TILES) * 256;    // 800000
        for (int i = t; i < 64 * 128; i += stride) {
            const int n = i >> 7, k = i & 127;
            Wn1p[i] = (__bf16)Wn1[k * 64 + n];
        }
        for (int i = t; i < 64 * 64; i += stride) {
            const int n = i >> 6, k = i & 63;
            We2p[i] = (__bf16)We2[k * 64 + n];
            Wx1p[i] = (__bf16)Wx1[k * 64 + n];
            Wn2p[i] = (__bf16)Wn2[k * 64 + n];
        }
        for (int n = t; n < N_NODES; n += stride)
            co4[n] = make_float4(coord[(size_t)n * 3], coord[(size_t)n * 3 + 1],
                                 coord[(size_t)n * 3 + 2], 0.0f);
        if (t < N_EDGES) atomicAdd(&cnt[dst[t]], 1);
    }
}

// ---------------- CSR scan: chunk scan then fused (bsum-scan + offsets) ----------------
__global__ void scan1_kernel(const int* __restrict__ cnt,
                             int* __restrict__ excl, int* __restrict__ bsum) {
    __shared__ int s[256];
    const int tid = threadIdx.x;
    const int i = blockIdx.x * 256 + tid;
    const int v = (i < N_NODES) ? cnt[i] : 0;
    s[tid] = v; __syncthreads();
#pragma unroll
    for (int off = 1; off < 256; off <<= 1) {
        int t = (tid >= off) ? s[tid - off] : 0;
        __syncthreads();
        s[tid] += t;
        __syncthreads();
    }
    if (i < N_NODES) excl[i] = s[tid] - v;
    if (tid == 255) bsum[blockIdx.x] = s[255];
}

__global__ void scan23_kernel(const int* __restrict__ bsum,
                              const int* __restrict__ excl,
                              int* __restrict__ offsets, int* __restrict__ cursor) {
    __shared__ int s[256];
    __shared__ int base;
    const int tid = threadIdx.x;
    const int bid = blockIdx.x;
    const int v = (tid < N_CHUNKS) ? bsum[tid] : 0;
    s[tid] = v; __syncthreads();
#pragma unroll
    for (int off = 1; off < 256; off <<= 1) {
        int t = (tid >= off) ? s[tid - off] : 0;
        __syncthreads();
        s[tid] += t;
        __syncthreads();
    }
    if (tid == 0) base = (bid > 0) ? s[bid - 1] : 0;
    __syncthreads();
    const int i = bid * 256 + tid;
    if (i < N_NODES) {
        const int o = base + excl[i];
        offsets[i] = o;
        cursor[i] = o;
    }
    if (bid == 0 && tid == 0) offsets[N_NODES] = N_EDGES;
}

__global__ void fill_v4(const int* __restrict__ src, const int* __restrict__ dst,
                        int* __restrict__ cursor,
                        int2* __restrict__ edge_p) {
    const int e = blockIdx.x * 256 + threadIdx.x;
    if (e < N_EDGES) {
        const int gs = src[e];
        const int gd = dst[e];
        const int p = atomicAdd(&cursor[gd], 1);
        edge_p[p] = make_int2(gs, gd);
    }
}

// ---------------- edge kernel v11: 2-edge ILP, 6 blocks/CU (no spills) ----------------
__global__ __launch_bounds__(256, 6)
void egnn_edge_mfma_v11(const __bf16* __restrict__ P1b,
                        const __bf16* __restrict__ P2b,
                        const int2* __restrict__ edge_p,
                        const float4* __restrict__ co4,
                        const float* __restrict__ We1,   // row 128 (radial) f32
                        const float* __restrict__ be2,
                        const float* __restrict__ bx1,
                        const float* __restrict__ Wx2,
                        const __bf16* __restrict__ We2p,
                        const __bf16* __restrict__ Wx1p,
                        float* __restrict__ h_neigh,     // [N*64] f32 accum
                        float* __restrict__ xs)          // [N*4]  f32 accum
{
    // wave-private LDS only (wave w owns rows w*32 .. w*32+31)
    __shared__ __bf16 sM[128 * STR2];
    __shared__ float  sCoef[128];

    const int t     = threadIdx.x;
    const int lane  = t & 63;
    const int w     = t >> 6;
    const int lr    = lane & 15;
    const int lk    = lane >> 4;
    const int j0    = blockIdx.x * 128;    // E = 6250*128, no tail
    const int rbase = w * 32;

    const int2 e0 = edge_p[j0 + rbase + lr];
    const int2 e1 = edge_p[j0 + rbase + 16 + lr];

    // ---- issue all scattered loads up front (two independent chains) ----
    const float4 cs0 = co4[e0.x], cd0 = co4[e0.y];
    const float4 cs1 = co4[e1.x], cd1 = co4[e1.y];
    const bf16x8 p1a0 = *(const bf16x8*)(P1b + (size_t)e0.x * 64 + lk * 8);
    const bf16x8 p1c0 = *(const bf16x8*)(P1b + (size_t)e0.x * 64 + 32 + lk * 8);
    const bf16x8 p2a0 = *(const bf16x8*)(P2b + (size_t)e0.y * 64 + lk * 8);
    const bf16x8 p2c0 = *(const bf16x8*)(P2b + (size_t)e0.y * 64 + 32 + lk * 8);
    const bf16x8 p1a1 = *(const bf16x8*)(P1b + (size_t)e1.x * 64 + lk * 8);
    const bf16x8 p1c1 = *(const bf16x8*)(P1b + (size_t)e1.x * 64 + 32 + lk * 8);
    const bf16x8 p2a1 = *(const bf16x8*)(P2b + (size_t)e1.y * 64 + lk * 8);
    const bf16x8 p2c1 = *(const bf16x8*)(P2b + (size_t)e1.y * 64 + 32 + lk * 8);

    // radial weight row (f32), this lane's column chunks
    const float4 w00 = *(const float4*)(We1 + 128 * 64 + lk * 8);
    const float4 w01 = *(const float4*)(We1 + 128 * 64 + lk * 8 + 4);
    const float4 w10 = *(const float4*)(We1 + 128 * 64 + 32 + lk * 8);
    const float4 w11 = *(const float4*)(We1 + 128 * 64 + 32 + lk * 8 + 4);
    const float wv0[8] = {w00.x, w00.y, w00.z, w00.w, w01.x, w01.y, w01.z, w01.w};
    const float wv1[8] = {w10.x, w10.y, w10.z, w10.w, w11.x, w11.y, w11.z, w11.w};

    // geometry
    const float dx0 = cs0.x - cd0.x, dy0 = cs0.y - cd0.y, dz0 = cs0.z - cd0.z;
    const float rad0 = dx0 * dx0 + dy0 * dy0 + dz0 * dz0;
    const float gi0 = fast_rcp(sqrtf(rad0) + EPS_F);
    const float gx0 = dx0 * gi0, gy0 = dy0 * gi0, gz0 = dz0 * gi0;
    const float dx1 = cs1.x - cd1.x, dy1 = cs1.y - cd1.y, dz1 = cs1.z - cd1.z;
    const float rad1 = dx1 * dx1 + dy1 * dy1 + dz1 * dz1;
    const float gi1 = fast_rcp(sqrtf(rad1) + EPS_F);
    const float gx1 = dx1 * gi1, gy1 = dy1 * gi1, gz1 = dz1 * gi1;

    f32x4 acc[4];

    // ================= group 0 =================
    {
        bf16x8 a0, a1;
#pragma unroll
        for (int u = 0; u < 8; ++u) {
            a0[u] = (__bf16)silu_f((float)p1a0[u] + (float)p2a0[u] + rad0 * wv0[u]);
            a1[u] = (__bf16)silu_f((float)p1c0[u] + (float)p2c0[u] + rad0 * wv1[u]);
        }
#pragma unroll
        for (int nt = 0; nt < 4; ++nt) {
            const float b0 = be2[nt * 16 + lr];
            acc[nt] = (f32x4){b0, b0, b0, b0};
            const __bf16* bp = We2p + (size_t)(nt * 16 + lr) * 64 + lk * 8;
            acc[nt] = __builtin_amdgcn_mfma_f32_16x16x32_bf16(a0, *(const bf16x8*)(bp),      acc[nt], 0, 0, 0);
            acc[nt] = __builtin_amdgcn_mfma_f32_16x16x32_bf16(a1, *(const bf16x8*)(bp + 32), acc[nt], 0, 0, 0);
        }
#pragma unroll
        for (int nt = 0; nt < 4; ++nt) {
            const int col = nt * 16 + lr;
#pragma unroll
            for (int r = 0; r < 4; ++r)
                sM[(rbase + lk * 4 + r) * STR2 + col] = (__bf16)silu_f(acc[nt][r]);
        }
        // layer 3 (coef)
        const bf16x8 m0 = *(const bf16x8*)&sM[(rbase + lr) * STR2 + lk * 8];
        const bf16x8 m1 = *(const bf16x8*)&sM[(rbase + lr) * STR2 + 32 + lk * 8];
#pragma unroll
        for (int nt = 0; nt < 4; ++nt) {
            const float b0 = bx1[nt * 16 + lr];
            acc[nt] = (f32x4){b0, b0, b0, b0};
            const __bf16* bp = Wx1p + (size_t)(nt * 16 + lr) * 64 + lk * 8;
            acc[nt] = __builtin_amdgcn_mfma_f32_16x16x32_bf16(m0, *(const bf16x8*)(bp),      acc[nt], 0, 0, 0);
            acc[nt] = __builtin_amdgcn_mfma_f32_16x16x32_bf16(m1, *(const bf16x8*)(bp + 32), acc[nt], 0, 0, 0);
        }
        float p[4] = {0.f, 0.f, 0.f, 0.f};
#pragma unroll
        for (int nt = 0; nt < 4; ++nt) {
            const float wv = Wx2[nt * 16 + lr];
#pragma unroll
            for (int r = 0; r < 4; ++r)
                p[r] += silu_f(acc[nt][r]) * wv;
        }
#pragma unroll
        for (int off = 1; off < 16; off <<= 1)
#pragma unroll
            for (int r = 0; r < 4; ++r)
                p[r] += __shfl_xor(p[r], off);
        if (lr == 0) {
#pragma unroll
            for (int r = 0; r < 4; ++r)
                sCoef[rbase + lk * 4 + r] = p[r];
        }
    }

    // ================= group 1 =================
    {
        bf16x8 a0, a1;
#pragma unroll
        for (int u = 0; u < 8; ++u) {
            a0[u] = (__bf16)silu_f((float)p1a1[u] + (float)p2a1[u] + rad1 * wv0[u]);
            a1[u] = (__bf16)silu_f((float)p1c1[u] + (float)p2c1[u] + rad1 * wv1[u]);
        }
#pragma unroll
        for (int nt = 0; nt < 4; ++nt) {
            const float b0 = be2[nt * 16 + lr];
            acc[nt] = (f32x4){b0, b0, b0, b0};
            const __bf16* bp = We2p + (size_t)(nt * 16 + lr) * 64 + lk * 8;
            acc[nt] = __builtin_amdgcn_mfma_f32_16x16x32_bf16(a0, *(const bf16x8*)(bp),      acc[nt], 0, 0, 0);
            acc[nt] = __builtin_amdgcn_mfma_f32_16x16x32_bf16(a1, *(const bf16x8*)(bp + 32), acc[nt], 0, 0, 0);
        }
#pragma unroll
        for (int nt = 0; nt < 4; ++nt) {
            const int col = nt * 16 + lr;
#pragma unroll
            for (int r = 0; r < 4; ++r)
                sM[(rbase + 16 + lk * 4 + r) * STR2 + col] = (__bf16)silu_f(acc[nt][r]);
        }
        // layer 3 (coef)
        const bf16x8 m0 = *(const bf16x8*)&sM[(rbase + 16 + lr) * STR2 + lk * 8];
        const bf16x8 m1 = *(const bf16x8*)&sM[(rbase + 16 + lr) * STR2 + 32 + lk * 8];
#pragma unroll
        for (int nt = 0; nt < 4; ++nt) {
            const float b0 = bx1[nt * 16 + lr];
            acc[nt] = (f32x4){b0, b0, b0, b0};
            const __bf16* bp = Wx1p + (size_t)(nt * 16 + lr) * 64 + lk * 8;
            acc[nt] = __builtin_amdgcn_mfma_f32_16x16x32_bf16(m0, *(const bf16x8*)(bp),      acc[nt], 0, 0, 0);
            acc[nt] = __builtin_amdgcn_mfma_f32_16x16x32_bf16(m1, *(const bf16x8*)(bp + 32), acc[nt], 0, 0, 0);
        }
        float p[4] = {0.f, 0.f, 0.f, 0.f};
#pragma unroll
        for (int nt = 0; nt < 4; ++nt) {
            const float wv = Wx2[nt * 16 + lr];
#pragma unroll
            for (int r = 0; r < 4; ++r)
                p[r] += silu_f(acc[nt][r]) * wv;
        }
#pragma unroll
        for (int off = 1; off < 16; off <<= 1)
#pragma unroll
            for (int r = 0; r < 4; ++r)
                p[r] += __shfl_xor(p[r], off);
        if (lr == 0) {
#pragma unroll
            for (int r = 0; r < 4; ++r)
                sCoef[rbase + 16 + lk * 4 + r] = p[r];
        }
    }

    // ---- column segment-reduce of 32 msg rows onto h_neigh ----
    {
        float accum = 0.0f;
        int cur = __shfl(e0.y, 0);
#pragma unroll
        for (int rr = 0; rr < 32; ++rr) {
            const int d = (rr < 16) ? __shfl(e0.y, rr) : __shfl(e1.y, rr - 16);
            const float v = (float)sM[(rbase + rr) * STR2 + lane];
            if (d != cur) {                   // wave-uniform branch
                atomicAdd(&h_neigh[(size_t)cur * 64 + lane], accum);
                accum = 0.0f; cur = d;
            }
            accum += v;
        }
        atomicAdd(&h_neigh[(size_t)cur * 64 + lane], accum);
    }

    // ---- xs: in-wave segmented shuffle-reduce, group 0 then group 1 ----
    {
        const float c = sCoef[rbase + lr];
        float vx = c * gx0, vy = c * gy0, vz = c * gz0;
        const int d = e0.y;
#pragma unroll
        for (int off = 1; off < 16; off <<= 1) {
            const int   od = __shfl(d,  lane + off);
            const float ox = __shfl(vx, lane + off);
            const float oy = __shfl(vy, lane + off);
            const float oz = __shfl(vz, lane + off);
            if ((lr + off < 16) && (od == d)) { vx += ox; vy += oy; vz += oz; }
        }
        const int pd = __shfl(d, lane - 1);
        const bool head = (lr == 0) || (pd != d);
        if (head && lk == 0) {
            atomicAdd(&xs[(size_t)d * 4 + 0], vx);
            atomicAdd(&xs[(size_t)d * 4 + 1], vy);
            atomicAdd(&xs[(size_t)d * 4 + 2], vz);
        }
    }
    {
        const float c = sCoef[rbase + 16 + lr];
        float vx = c * gx1, vy = c * gy1, vz = c * gz1;
        const int d = e1.y;
#pragma unroll
        for (int off = 1; off < 16; off <<= 1) {
            const int   od = __shfl(d,  lane + off);
            const float ox = __shfl(vx, lane + off);
            const float oy = __shfl(vy, lane + off);
            const float oz = __shfl(vz, lane + off);
            if ((lr + off < 16) && (od == d)) { vx += ox; vy += oy; vz += oz; }
        }
        const int pd = __shfl(d, lane - 1);
        const bool head = (lr == 0) || (pd != d);
        if (head && lk == 0) {
            atomicAdd(&xs[(size_t)d * 4 + 0], vx);
            atomicAdd(&xs[(size_t)d * 4 + 1], vy);
            atomicAdd(&xs[(size_t)d * 4 + 2], vz);
        }
    }
}

// ---------------- node kernel v6: f32 reads, reg A-fragments ----------------
__global__ __launch_bounds__(256, 8)
void egnn_node_mfma_v6(const float* __restrict__ node_feat,
                       const float* __restrict__ coord,
                       const int* __restrict__ offsets,
                       const float* __restrict__ h_neigh,   // [N*64] f32
                       const float4* __restrict__ xs,       // [N]
                       const float* __restrict__ bn1,
                       const float* __restrict__ bn2,
                       const __bf16* __restrict__ Wn1p,
                       const __bf16* __restrict__ Wn2p,
                       float* __restrict__ out_h,
                       float* __restrict__ out_x)
{
    __shared__ __bf16 sT[64 * STR2];   // wave-private slices

    const int t    = threadIdx.x;
    const int lane = t & 63;
    const int w    = t >> 6;
    const int lr   = lane & 15;
    const int lk   = lane >> 4;
    const int n0   = blockIdx.x * 64;
    const int myrow = n0 + w * 16 + lr;
    const bool valid = (myrow < N_NODES);

    const bf16x8 zf = {(__bf16)0.f, (__bf16)0.f, (__bf16)0.f, (__bf16)0.f,
                       (__bf16)0.f, (__bf16)0.f, (__bf16)0.f, (__bf16)0.f};

    bf16x8 a0 = zf, a1 = zf, a2 = zf, a3 = zf;
    if (valid) {
        const float* np = node_feat + (size_t)myrow * 64;
        a0 = cvt8(*(const float4*)(np + lk * 8),      *(const float4*)(np + lk * 8 + 4));
        a1 = cvt8(*(const float4*)(np + 32 + lk * 8), *(const float4*)(np + 32 + lk * 8 + 4));
        const float* hp = h_neigh + (size_t)myrow * 64;
        a2 = cvt8(*(const float4*)(hp + lk * 8),      *(const float4*)(hp + lk * 8 + 4));
        a3 = cvt8(*(const float4*)(hp + 32 + lk * 8), *(const float4*)(hp + 32 + lk * 8 + 4));
    }

    // coordinate update (first wave, one thread per node)
    if (t < 64) {
        const int n = n0 + t;
        if (n < N_NODES) {
            const int deg = offsets[n + 1] - offsets[n];
            const float inv = fast_rcp(fmaxf((float)deg, 1.0f));
            const float4 xv = xs[n];
            out_x[(size_t)n * 3 + 0] = coord[(size_t)n * 3 + 0] + xv.x * inv;
            out_x[(size_t)n * 3 + 1] = coord[(size_t)n * 3 + 1] + xv.y * inv;
            out_x[(size_t)n * 3 + 2] = coord[(size_t)n * 3 + 2] + xv.z * inv;
        }
    }

    f32x4 acc[4];

    // ---- node layer 1 (K=128) ----
#pragma unroll
    for (int nt = 0; nt < 4; ++nt) {
        const float b0 = bn1[nt * 16 + lr];
        acc[nt] = (f32x4){b0, b0, b0, b0};
        const __bf16* bp = Wn1p + (size_t)(nt * 16 + lr) * 128 + lk * 8;
        acc[nt] = __builtin_amdgcn_mfma_f32_16x16x32_bf16(a0, *(const bf16x8*)(bp),      acc[nt], 0, 0, 0);
        acc[nt] = __builtin_amdgcn_mfma_f32_16x16x32_bf16(a1, *(const bf16x8*)(bp + 32), acc[nt], 0, 0, 0);
        acc[nt] = __builtin_amdgcn_mfma_f32_16x16x32_bf16(a2, *(const bf16x8*)(bp + 64), acc[nt], 0, 0, 0);
        acc[nt] = __builtin_amdgcn_mfma_f32_16x16x32_bf16(a3, *(const bf16x8*)(bp + 96), acc[nt], 0, 0, 0);
    }
#pragma unroll
    for (int nt = 0; nt < 4; ++nt) {
        const int col = nt * 16 + lr;
#pragma unroll
        for (int rr = 0; rr < 4; ++rr)
            sT[(w * 16 + lk * 4 + rr) * STR2 + col] = (__bf16)silu_f(acc[nt][rr]);
    }

    // ---- node layer 2 (K=64), direct stores ----
    {
        const bf16x8 b0f = *(const bf16x8*)&sT[(w * 16 + lr) * STR2 + lk * 8];
        const bf16x8 b1f = *(const bf16x8*)&sT[(w * 16 + lr) * STR2 + 32 + lk * 8];
#pragma unroll
        for (int nt = 0; nt < 4; ++nt) {
            const float b0 = bn2[nt * 16 + lr];
            acc[nt] = (f32x4){b0, b0, b0, b0};
            const __bf16* bp = Wn2p + (size_t)(nt * 16 + lr) * 64 + lk * 8;
            acc[nt] = __builtin_amdgcn_mfma_f32_16x16x32_bf16(b0f, *(const bf16x8*)(bp),      acc[nt], 0, 0, 0);
            acc[nt] = __builtin_amdgcn_mfma_f32_16x16x32_bf16(b1f, *(const bf16x8*)(bp + 32), acc[nt], 0, 0, 0);
        }
#pragma unroll
        for (int nt = 0; nt < 4; ++nt) {
            const int col = nt * 16 + lr;
#pragma unroll
            for (int rr = 0; rr < 4; ++rr) {
                const int row = n0 + w * 16 + lk * 4 + rr;
                if (row < N_NODES)
                    out_h[(size_t)row * 64 + col] = acc[nt][rr];
            }
        }
    }
}

// ================= fallback path (atomics) =================
__global__ void prep_kernel(const float* __restrict__ node_feat,
                            const float* __restrict__ We1,
                            const float* __restrict__ We2,
                            const float* __restrict__ Wx1,
                            const float* __restrict__ Wn1,
                            const float* __restrict__ Wn2,
                            __bf16* __restrict__ nfb,
                            __bf16* __restrict__ We1p,
                            __bf16* __restrict__ We2p,
                            __bf16* __restrict__ Wx1p,
                            __bf16* __restrict__ Wn1p,
                            __bf16* __restrict__ Wn2p)
{
    const int t = blockIdx.x * 256 + threadIdx.x;
    const int stride = gridDim.x * 256;
    for (int i = t; i < N_NODES * 64; i += stride)
        nfb[i] = (__bf16)node_feat[i];
    for (int i = t; i < 64 * 128; i += stride) {
        const int n = i >> 7, k = i & 127;
        We1p[i] = (__bf16)We1[k * 64 + n];
        Wn1p[i] = (__bf16)Wn1[k * 64 + n];
    }
    for (int i = t; i < 64 * 64; i += stride) {
        const int n = i >> 6, k = i & 63;
        We2p[i] = (__bf16)We2[k * 64 + n];
        Wx1p[i] = (__bf16)Wx1[k * 64 + n];
        Wn2p[i] = (__bf16)Wn2[k * 64 + n];
    }
}

__global__ __launch_bounds__(256, 4)
void egnn_edge_mfma_atomic(const float* __restrict__ node_feat,
                           const float* __restrict__ coord,
                           const int* __restrict__ src,
                           const int* __restrict__ dst,
                           const float* __restrict__ We1,
                           const float* __restrict__ be1,
                           const float* __restrict__ be2,
                           const float* __restrict__ bx1,
                           const float* __restrict__ Wx2,
                           const __bf16* __restrict__ We1p,
                           const __bf16* __restrict__ We2p,
                           const __bf16* __restrict__ Wx1p,
                           float* __restrict__ h_neigh,
                           float* __restrict__ x_sum,
                           float* __restrict__ deg)
{
    __shared__ __bf16 sFb[64 * STR1];
    __shared__ __bf16 sT [64 * STR2];
    __shared__ __bf16 sM [64 * STR2];
    __shared__ float  sRad[64];
    __shared__ float  sXd[64][3];
    __shared__ int    sDst[64];

    const int t  = threadIdx.x;
    const int e0 = blockIdx.x * 64;

    {
        const int e = t >> 2, sub = t & 3;
        const int gs = src[e0 + e];
        const int gd = dst[e0 + e];
        const float4* rs = (const float4*)(node_feat + (size_t)gs * 64) + sub * 4;
        const float4* rd = (const float4*)(node_feat + (size_t)gd * 64) + sub * 4;
#pragma unroll
        for (int q = 0; q < 4; ++q) {
            float4 a = rs[q];
            float4 b = rd[q];
            *(bf16x4*)&sFb[e * STR1 + sub * 16 + 4 * q] =
                (bf16x4){(__bf16)a.x, (__bf16)a.y, (__bf16)a.z, (__bf16)a.w};
            *(bf16x4*)&sFb[e * STR1 + 64 + sub * 16 + 4 * q] =
                (bf16x4){(__bf16)b.x, (__bf16)b.y, (__bf16)b.z, (__bf16)b.w};
        }
    }
    if (t < 64) {
        const int e  = t;
        const int gs = src[e0 + e];
        const int gd = dst[e0 + e];
        float dx = coord[(size_t)gs * 3 + 0] - coord[(size_t)gd * 3 + 0];
        float dy = coord[(size_t)gs * 3 + 1] - coord[(size_t)gd * 3 + 1];
        float dz = coord[(size_t)gs * 3 + 2] - coord[(size_t)gd * 3 + 2];
        float radial = dx * dx + dy * dy + dz * dz;
        sRad[e] = radial;
        float inv = fast_rcp(sqrtf(radial) + EPS_F);
        sXd[e][0] = dx * inv; sXd[e][1] = dy * inv; sXd[e][2] = dz * inv;
        sDst[e] = gd;
    }
    __syncthreads();

    const int lane = t & 63;
    const int w    = t >> 6;
    const int lr   = lane & 15;
    const int lk   = lane >> 4;

    f32x4 acc[4];
    {
#pragma unroll
        for (int nt = 0; nt < 4; ++nt) {
            const int col = nt * 16 + lr;
            const float b0 = be1[col];
            const float wr = We1[128 * 64 + col];
#pragma unroll
            for (int r = 0; r < 4; ++r)
                acc[nt][r] = b0 + sRad[w * 16 + lk * 4 + r] * wr;
        }
        const int arow = w * 16 + lr;
#pragma unroll
        for (int ks = 0; ks < 4; ++ks) {
            bf16x8 a = *(const bf16x8*)&sFb[arow * STR1 + ks * 32 + lk * 8];
#pragma unroll
            for (int nt = 0; nt < 4; ++nt) {
                bf16x8 b = *(const bf16x8*)&We1p[(nt * 16 + lr) * 128 + ks * 32 + lk * 8];
                acc[nt] = __builtin_amdgcn_mfma_f32_16x16x32_bf16(a, b, acc[nt], 0, 0, 0);
            }
        }
#pragma unroll
        for (int nt = 0; nt < 4; ++nt) {
            const int col = nt * 16 + lr;
#pragma unroll
            for (int r = 0; r < 4; ++r) {
                const int row = w * 16 + lk * 4 + r;
                sT[row * STR2 + col] = (__bf16)silu_f(acc[nt][r]);
            }
        }
    }
    __syncthreads();
    {
#pragma unroll
        for (int nt = 0; nt < 4; ++nt) {
            const float b0 = be2[nt * 16 + lr];
            acc[nt] = (f32x4){b0, b0, b0, b0};
        }
        const int arow = w * 16 + lr;
#pragma unroll
        for (int ks = 0; ks < 2; ++ks) {
            bf16x8 a = *(const bf16x8*)&sT[arow * STR2 + ks * 32 + lk * 8];
#pragma unroll
            for (int nt = 0; nt < 4; ++nt) {
                bf16x8 b = *(const bf16x8*)&We2p[(nt * 16 + lr) * 64 + ks * 32 + lk * 8];
                acc[nt] = __builtin_amdgcn_mfma_f32_16x16x32_bf16(a, b, acc[nt], 0, 0, 0);
            }
        }
#pragma unroll
        for (int nt = 0; nt < 4; ++nt) {
            const int col = nt * 16 + lr;
#pragma unroll
            for (int r = 0; r < 4; ++r) {
                const int row = w * 16 + lk * 4 + r;
                const float v = silu_f(acc[nt][r]);
                sM[row * STR2 + col] = (__bf16)v;
                atomicAdd(&h_neigh[(size_t)sDst[row] * 64 + col], v);
            }
        }
    }
    __syncthreads();
    {
#pragma unroll
        for (int nt = 0; nt < 4; ++nt) {
            const float b0 = bx1[nt * 16 + lr];
            acc[nt] = (f32x4){b0, b0, b0, b0};
        }
        const int arow = w * 16 + lr;
#pragma unroll
        for (int ks = 0; ks < 2; ++ks) {
            bf16x8 a = *(const bf16x8*)&sM[arow * STR2 + ks * 32 + lk * 8];
#pragma unroll
            for (int nt = 0; nt < 4; ++nt) {
                bf16x8 b = *(const bf16x8*)&Wx1p[(nt * 16 + lr) * 64 + ks * 32 + lk * 8];
                acc[nt] = __builtin_amdgcn_mfma_f32_16x16x32_bf16(a, b, acc[nt], 0, 0, 0);
            }
        }
        float p[4] = {0.f, 0.f, 0.f, 0.f};
#pragma unroll
        for (int nt = 0; nt < 4; ++nt) {
            const float wv = Wx2[nt * 16 + lr];
#pragma unroll
            for (int r = 0; r < 4; ++r)
                p[r] += silu_f(acc[nt][r]) * wv;
        }
#pragma unroll
        for (int off = 1; off < 16; off <<= 1)
#pragma unroll
            for (int r = 0; r < 4; ++r)
                p[r] += __shfl_xor(p[r], off);
        if (lr == 0) {
#pragma unroll
            for (int r = 0; r < 4; ++r) {
                const int e  = w * 16 + lk * 4 + r;
                const int gd = sDst[e];
                const float coef = p[r];
                atomicAdd(&x_sum[(size_t)gd * 3 + 0], coef * sXd[e][0]);
                atomicAdd(&x_sum[(size_t)gd * 3 + 1], coef * sXd[e][1]);
                atomicAdd(&x_sum[(size_t)gd * 3 + 2], coef * sXd[e][2]);
                atomicAdd(&deg[gd], 1.0f);
            }
        }
    }
}

template<int KDIM>
__device__ __forceinline__ void tile_gemm64(const float* __restrict__ A, int astride,
                                            const float* __restrict__ B,
                                            float acc[4][4], int t)
{
    const int tx = t & 15;
    const int ty = t >> 4;
#pragma unroll
    for (int i = 0; i < 4; ++i)
#pragma unroll
        for (int j = 0; j < 4; ++j) acc[i][j] = 0.0f;

    for (int k = 0; k < KDIM; k += 4) {
        float bv[4][4];
#pragma unroll
        for (int kk = 0; kk < 4; ++kk) {
            float4 bq = *(const float4*)(B + (size_t)(k + kk) * 64 + tx * 4);
            bv[kk][0] = bq.x; bv[kk][1] = bq.y; bv[kk][2] = bq.z; bv[kk][3] = bq.w;
        }
#pragma unroll
        for (int i = 0; i < 4; ++i) {
            float4 aq = *(const float4*)(A + (size_t)(ty * 4 + i) * astride + k);
            float av[4] = {aq.x, aq.y, aq.z, aq.w};
#pragma unroll
            for (int kk = 0; kk < 4; ++kk)
#pragma unroll
                for (int j = 0; j < 4; ++j)
                    acc[i][j] = fmaf(av[kk], bv[kk][j], acc[i][j]);
        }
    }
}

__global__ __launch_bounds__(256, 2)
void egnn_node_kernel(const float* __restrict__ node_feat,
                      const float* __restrict__ coord,
                      const float* __restrict__ Wn1, const float* __restrict__ bn1,
                      const float* __restrict__ Wn2, const float* __restrict__ bn2,
                      const float* __restrict__ h_neigh,
                      const float* __restrict__ x_sum,
                      const float* __restrict__ deg,
                      float* __restrict__ out_h,
                      float* __restrict__ out_x)
{
    __shared__ float sF[64][132];
    __shared__ float sT2[64][68];

    const int t  = threadIdx.x;
    const int n0 = blockIdx.x * 64;

    {
        const int r = t >> 2;
        const int sub = t & 3;
        const int n = n0 + r;
        if (n < N_NODES) {
            const float* rowsrc = (sub < 2) ? (node_feat + (size_t)n * 64 + sub * 32)
                                            : (h_neigh  + (size_t)n * 64 + (sub - 2) * 32);
#pragma unroll
            for (int q = 0; q < 8; ++q)
                *(float4*)&sF[r][sub * 32 + 4 * q] = *(const float4*)(rowsrc + 4 * q);
        } else {
#pragma unroll
            for (int q = 0; q < 8; ++q)
                *(float4*)&sF[r][sub * 32 + 4 * q] = make_float4(0.f, 0.f, 0.f, 0.f);
        }
    }
    __syncthreads();

    const int tx = t & 15;
    const int ty = t >> 4;
    float acc[4][4];

    tile_gemm64<128>(&sF[0][0], 132, Wn1, acc, t);
    {
        float4 bq = *(const float4*)(bn1 + tx * 4);
        float bv[4] = {bq.x, bq.y, bq.z, bq.w};
#pragma unroll
        for (int i = 0; i < 4; ++i) {
            float4 o;
            o.x = silu_f(acc[i][0] + bv[0]);
            o.y = silu_f(acc[i][1] + bv[1]);
            o.z = silu_f(acc[i][2] + bv[2]);
            o.w = silu_f(acc[i][3] + bv[3]);
            *(float4*)&sT2[ty * 4 + i][tx * 4] = o;
        }
    }
    __syncthreads();

    tile_gemm64<64>(&sT2[0][0], 68, Wn2, acc, t);
    {
        float4 bq = *(const float4*)(bn2 + tx * 4);
        float bv[4] = {bq.x, bq.y, bq.z, bq.w};
#pragma unroll
        for (int i = 0; i < 4; ++i) {
            const int n = n0 + ty * 4 + i;
            if (n < N_NODES) {
                float4 o;
                o.x = acc[i][0] + bv[0];
                o.y = acc[i][1] + bv[1];
                o.z = acc[i][2] + bv[2];
                o.w = acc[i][3] + bv[3];
                *(float4*)&out_h[(size_t)n * 64 + tx * 4] = o;
            }
        }
    }

    if (t < 64) {
        const int n = n0 + t;
        if (n < N_NODES) {
            const float d = deg[n];
            const float inv = fast_rcp(fmaxf(d, 1.0f));
#pragma unroll
            for (int c = 0; c < 3; ++c)
                out_x[(size_t)n * 3 + c] = coord[(size_t)n * 3 + c]
                                         + x_sum[(size_t)n * 3 + c] * inv;
        }
    }
}

// ================= host =================
extern "C" void kernel_launch(void* const* d_in, const int* in_sizes, int n_in,
                              void* d_out, int out_size, void* d_ws, size_t ws_size,
                              hipStream_t stream) {
    const float* node_feat = (const float*)d_in[0];
    const float* coord     = (const float*)d_in[1];
    const int*   src       = (const int*)d_in[2];
    const int*   dst       = (const int*)d_in[3];
    const float* We1 = (const float*)d_in[4];
    const float* be1 = (const float*)d_in[5];
    const float* We2 = (const float*)d_in[6];
    const float* be2 = (const float*)d_in[7];
    const float* Wx1 = (const float*)d_in[8];
    const float* bx1 = (const float*)d_in[9];
    const float* Wx2 = (const float*)d_in[10];
    const float* Wn1 = (const float*)d_in[11];
    const float* bn1 = (const float*)d_in[12];
    const float* Wn2 = (const float*)d_in[13];
    const float* bn2 = (const float*)d_in[14];

    float* out_h = (float*)d_out;
    float* out_x = out_h + (size_t)N_NODES * 64;

    // ---- workspace layout (fast path); h_neigh/xs/cnt contiguous for ONE memset ----
    char* ws = (char*)d_ws;
    size_t off = 0;
    auto take = [&](size_t bytes) { char* p = ws + off; off = (off + bytes + 255) & ~(size_t)255; return p; };

    float*  h_neigh = (float*)take((size_t)N_NODES * 64 * 4);   // 12.8MB
    float*  xs      = (float*)take((size_t)N_NODES * 16);       // 800KB
    int*    cnt     = (int*)take((size_t)N_NODES * 4);          // 200KB
    const size_t zero_span = off;                                // one memset covers all
    int2*   edge_p  = (int2*)take((size_t)N_EDGES * 8);
    float4* co4     = (float4*)take((size_t)N_NODES * 16);
    __bf16* P1b     = (__bf16*)take((size_t)N_NODES * 64 * 2);
    __bf16* P2b     = (__bf16*)take((size_t)N_NODES * 64 * 2);
    int*    offsets = (int*)take((size_t)(N_NODES + 1) * 4);
    int*    cursor  = (int*)take((size_t)N_NODES * 4);
    int*    excl    = (int*)take((size_t)N_NODES * 4);
    int*    bsum    = (int*)take(1024);
    __bf16* We2p    = (__bf16*)take(64 * 64 * 2);
    __bf16* Wx1p    = (__bf16*)take(64 * 64 * 2);
    __bf16* Wn1p    = (__bf16*)take(64 * 128 * 2);
    __bf16* Wn2p    = (__bf16*)take(64 * 64 * 2);
    const size_t needed = off;

    if (ws_size >= needed) {
        hipMemsetAsync(d_ws, 0, zero_span, stream);

        // one fused launch: pgemm tiles (blocks 0..781) | pack+co4+histogram (rest)
        fused_prep<<<N_TILES + (N_EDGES + 255) / 256, 256, 0, stream>>>(
            node_feat, coord, dst,
            We1, be1, We2, Wx1, Wn1, Wn2,
            We2p, Wx1p, Wn1p, Wn2p, co4, cnt, P1b, P2b);

        scan1_kernel<<<N_CHUNKS, 256, 0, stream>>>(cnt, excl, bsum);
        scan23_kernel<<<N_CHUNKS, 256, 0, stream>>>(bsum, excl, offsets, cursor);
        fill_v4<<<(N_EDGES + 255) / 256, 256, 0, stream>>>(src, dst, cursor, edge_p);

        egnn_edge_mfma_v11<<<N_EDGES / 128, 256, 0, stream>>>(
            P1b, P2b, edge_p, co4,
            We1, be2, bx1, Wx2,
            We2p, Wx1p,
            h_neigh, xs);

        egnn_node_mfma_v6<<<(N_NODES + 63) / 64, 256, 0, stream>>>(
            node_feat, coord, offsets, h_neigh, (const float4*)xs,
            bn1, bn2, Wn1p, Wn2p, out_h, out_x);
    } else {
        // ======== fallback: atomic path ========
        float* fh_neigh = (float*)d_ws;
        float* fx_sum   = fh_neigh + (size_t)N_NODES * 64;
        float* fdeg     = fx_sum + (size_t)N_NODES * 3;
        __bf16* fnfb    = (__bf16*)(fdeg + N_NODES);
        __bf16* fWe1p   = fnfb + (size_t)N_NODES * 64;
        __bf16* fWe2p   = fWe1p + 64 * 128;
        __bf16* fWx1p   = fWe2p + 64 * 64;
        __bf16* fWn1p   = fWx1p + 64 * 64;
        __bf16* fWn2p   = fWn1p + 64 * 128;

        hipMemsetAsync(d_ws, 0, (size_t)N_NODES * 68 * sizeof(float), stream);
        prep_kernel<<<2048, 256, 0, stream>>>(node_feat, We1, We2, Wx1, Wn1, Wn2,
                                              fnfb, fWe1p, fWe2p, fWx1p, fWn1p, fWn2p);
        egnn_edge_mfma_atomic<<<N_EDGES / 64, 256, 0, stream>>>(
            node_feat, coord, src, dst,
            We1, be1, be2, bx1, Wx2,
            fWe1p, fWe2p, fWx1p,
            fh_neigh, fx_sum, fdeg);
        egnn_node_kernel<<<(N_NODES + 63) / 64, 256, 0, stream>>>(
            node_feat, coord, Wn1, bn1, Wn2, bn2,
            fh_neigh, fx_sum, fdeg, out_h, out_x);
    }
}

// Round 14
// 256.093 us; speedup vs baseline: 1.1407x; 1.0175x over previous
//
#include <hip/hip_runtime.h>
#include <math.h>

#define N_NODES 50000
#define N_EDGES 800000
#define EPS_F 1e-30f
#define N_TILES 782     // ceil(N_NODES/64)  (pgemm blocks)
#define N_CHUNKS 196    // ceil(N_NODES/256) (scan chunks)

typedef __bf16 bf16x8 __attribute__((ext_vector_type(8)));
typedef __bf16 bf16x4 __attribute__((ext_vector_type(4)));
typedef float  f32x4  __attribute__((ext_vector_type(4)));

#define STR1 136   // 128-wide bf16 tile row stride (fallback kernel)
#define STR2 72    // 64-wide bf16 tile row stride (144B)

// 1-ulp hardware reciprocal: avoids the IEEE div sequence (~10 VALU ops)
__device__ __forceinline__ float fast_rcp(float x) {
    float r;
    asm("v_rcp_f32 %0, %1" : "=v"(r) : "v"(x));
    return r;
}

__device__ __forceinline__ float silu_f(float x) {
    return x * fast_rcp(1.0f + __expf(-x));
}

__device__ __forceinline__ bf16x8 cvt8(float4 u0, float4 u1) {
    return (bf16x8){(__bf16)u0.x, (__bf16)u0.y, (__bf16)u0.z, (__bf16)u0.w,
                    (__bf16)u1.x, (__bf16)u1.y, (__bf16)u1.z, (__bf16)u1.w};
}

// ---------------- fused prologue: [pgemm tiles | weight pack + co4 + histogram] ----------------
__global__ void fused_prep(const float* __restrict__ node_feat,
                           const float* __restrict__ coord,
                           const int* __restrict__ dst,
                           const float* __restrict__ We1,   // [129][64] f32
                           const float* __restrict__ be1,
                           const float* __restrict__ We2,
                           const float* __restrict__ Wx1,
                           const float* __restrict__ Wn1,
                           const float* __restrict__ Wn2,
                           __bf16* __restrict__ We2p,
                           __bf16* __restrict__ Wx1p,
                           __bf16* __restrict__ Wn1p,
                           __bf16* __restrict__ Wn2p,
                           float4* __restrict__ co4,
                           int* __restrict__ cnt,           // pre-zeroed
                           __bf16* __restrict__ P1b,
                           __bf16* __restrict__ P2b)
{
    __shared__ __bf16 sC[64 * STR2];

    if (blockIdx.x < N_TILES) {
        // ---- pgemm tile: P1 = nf@We1[0:64]+be1, P2 = nf@We1[64:128] ----
        const int t    = threadIdx.x;
        const int lane = t & 63;
        const int w    = t >> 6;
        const int lr   = lane & 15;
        const int lk   = lane >> 4;
        const int n0   = blockIdx.x * 64;
        const int myrow = n0 + w * 16 + lr;
        const bool valid = (myrow < N_NODES);

        const bf16x8 zf = {(__bf16)0.f, (__bf16)0.f, (__bf16)0.f, (__bf16)0.f,
                           (__bf16)0.f, (__bf16)0.f, (__bf16)0.f, (__bf16)0.f};
        bf16x8 a0 = zf, a1 = zf;
        if (valid) {
            const float* np = node_feat + (size_t)myrow * 64;
            a0 = cvt8(*(const float4*)(np + lk * 8),      *(const float4*)(np + lk * 8 + 4));
            a1 = cvt8(*(const float4*)(np + 32 + lk * 8), *(const float4*)(np + 32 + lk * 8 + 4));
        }

        f32x4 acc[4];
#pragma unroll
        for (int pass = 0; pass < 2; ++pass) {
#pragma unroll
            for (int nt = 0; nt < 4; ++nt) {
                const int col = nt * 16 + lr;
                const float b0 = (pass == 0) ? be1[col] : 0.0f;
                acc[nt] = (f32x4){b0, b0, b0, b0};
                // transpose-on-load B fragments from f32 We1 (33KB table, L1-hot)
                const float* wp0 = We1 + (size_t)(pass * 64 + lk * 8) * 64 + col;
                const float* wp1 = wp0 + 32 * 64;
                bf16x8 b0f, b1f;
#pragma unroll
                for (int j = 0; j < 8; ++j) {
                    b0f[j] = (__bf16)wp0[j * 64];
                    b1f[j] = (__bf16)wp1[j * 64];
                }
                acc[nt] = __builtin_amdgcn_mfma_f32_16x16x32_bf16(a0, b0f, acc[nt], 0, 0, 0);
                acc[nt] = __builtin_amdgcn_mfma_f32_16x16x32_bf16(a1, b1f, acc[nt], 0, 0, 0);
            }
#pragma unroll
            for (int nt = 0; nt < 4; ++nt) {
                const int col = nt * 16 + lr;
#pragma unroll
                for (int r = 0; r < 4; ++r)
                    sC[(w * 16 + lk * 4 + r) * STR2 + col] = (__bf16)acc[nt][r];
            }
            if (valid) {
                __bf16* out = (pass == 0) ? P1b : P2b;
                bf16x8 v0 = *(const bf16x8*)&sC[(w * 16 + lr) * STR2 + lk * 8];
                bf16x8 v1 = *(const bf16x8*)&sC[(w * 16 + lr) * STR2 + 32 + lk * 8];
                *(bf16x8*)(out + (size_t)myrow * 64 + lk * 8)      = v0;
                *(bf16x8*)(out + (size_t)myrow * 64 + 32 + lk * 8) = v1;
            }
            __syncthreads();   // sC reuse between passes
        }
    } else {
        // ---- pack weights + co4 + histogram ----
        const int g = blockIdx.x - N_TILES;
        const int t = g * 256 + threadIdx.x;
        const int stride = (gridDim.x - N_TILES) * 256;    // 800000
        for (int i = t; i < 64 * 128; i += stride) {
            const int n = i >> 7, k = i & 127;
            Wn1p[i] = (__bf16)Wn1[k * 64 + n];
        }
        for (int i = t; i < 64 * 64; i += stride) {
            const int n = i >> 6, k = i & 63;
            We2p[i] = (__bf16)We2[k * 64 + n];
            Wx1p[i] = (__bf16)Wx1[k * 64 + n];
            Wn2p[i] = (__bf16)Wn2[k * 64 + n];
        }
        for (int n = t; n < N_NODES; n += stride)
            co4[n] = make_float4(coord[(size_t)n * 3], coord[(size_t)n * 3 + 1],
                                 coord[(size_t)n * 3 + 2], 0.0f);
        if (t < N_EDGES) atomicAdd(&cnt[dst[t]], 1);
    }
}

// ---------------- CSR scan: chunk scan then fused (bsum-scan + offsets) ----------------
__global__ void scan1_kernel(const int* __restrict__ cnt,
                             int* __restrict__ excl, int* __restrict__ bsum) {
    __shared__ int s[256];
    const int tid = threadIdx.x;
    const int i = blockIdx.x * 256 + tid;
    const int v = (i < N_NODES) ? cnt[i] : 0;
    s[tid] = v; __syncthreads();
#pragma unroll
    for (int off = 1; off < 256; off <<= 1) {
        int t = (tid >= off) ? s[tid - off] : 0;
        __syncthreads();
        s[tid] += t;
        __syncthreads();
    }
    if (i < N_NODES) excl[i] = s[tid] - v;
    if (tid == 255) bsum[blockIdx.x] = s[255];
}

__global__ void scan23_kernel(const int* __restrict__ bsum,
                              const int* __restrict__ excl,
                              int* __restrict__ offsets, int* __restrict__ cursor) {
    __shared__ int s[256];
    __shared__ int base;
    const int tid = threadIdx.x;
    const int bid = blockIdx.x;
    const int v = (tid < N_CHUNKS) ? bsum[tid] : 0;
    s[tid] = v; __syncthreads();
#pragma unroll
    for (int off = 1; off < 256; off <<= 1) {
        int t = (tid >= off) ? s[tid - off] : 0;
        __syncthreads();
        s[tid] += t;
        __syncthreads();
    }
    if (tid == 0) base = (bid > 0) ? s[bid - 1] : 0;
    __syncthreads();
    const int i = bid * 256 + tid;
    if (i < N_NODES) {
        const int o = base + excl[i];
        offsets[i] = o;
        cursor[i] = o;
    }
    if (bid == 0 && tid == 0) offsets[N_NODES] = N_EDGES;
}

__global__ void fill_v4(const int* __restrict__ src, const int* __restrict__ dst,
                        int* __restrict__ cursor,
                        int2* __restrict__ edge_p) {
    const int e = blockIdx.x * 256 + threadIdx.x;
    if (e < N_EDGES) {
        const int gs = src[e];
        const int gd = dst[e];
        const int p = atomicAdd(&cursor[gd], 1);
        edge_p[p] = make_int2(gs, gd);
    }
}

// ---------------- edge kernel v9 (proven best): 2-edge ILP, (256,4), no spills ----------------
__global__ __launch_bounds__(256, 4)
void egnn_edge_mfma_v9(const __bf16* __restrict__ P1b,
                       const __bf16* __restrict__ P2b,
                       const int2* __restrict__ edge_p,
                       const float4* __restrict__ co4,
                       const float* __restrict__ We1,   // row 128 (radial) f32
                       const float* __restrict__ be2,
                       const float* __restrict__ bx1,
                       const float* __restrict__ Wx2,
                       const __bf16* __restrict__ We2p,
                       const __bf16* __restrict__ Wx1p,
                       float* __restrict__ h_neigh,     // [N*64] f32 accum
                       float* __restrict__ xs)          // [N*4]  f32 accum
{
    // wave-private LDS only (wave w owns rows w*32 .. w*32+31)
    __shared__ __bf16 sM[128 * STR2];
    __shared__ float  sCoef[128];

    const int t     = threadIdx.x;
    const int lane  = t & 63;
    const int w     = t >> 6;
    const int lr    = lane & 15;
    const int lk    = lane >> 4;
    const int j0    = blockIdx.x * 128;    // E = 6250*128, no tail
    const int rbase = w * 32;

    const int2 e0 = edge_p[j0 + rbase + lr];
    const int2 e1 = edge_p[j0 + rbase + 16 + lr];

    // ---- issue all scattered loads up front (two independent chains) ----
    const float4 cs0 = co4[e0.x], cd0 = co4[e0.y];
    const float4 cs1 = co4[e1.x], cd1 = co4[e1.y];
    const bf16x8 p1a0 = *(const bf16x8*)(P1b + (size_t)e0.x * 64 + lk * 8);
    const bf16x8 p1c0 = *(const bf16x8*)(P1b + (size_t)e0.x * 64 + 32 + lk * 8);
    const bf16x8 p2a0 = *(const bf16x8*)(P2b + (size_t)e0.y * 64 + lk * 8);
    const bf16x8 p2c0 = *(const bf16x8*)(P2b + (size_t)e0.y * 64 + 32 + lk * 8);
    const bf16x8 p1a1 = *(const bf16x8*)(P1b + (size_t)e1.x * 64 + lk * 8);
    const bf16x8 p1c1 = *(const bf16x8*)(P1b + (size_t)e1.x * 64 + 32 + lk * 8);
    const bf16x8 p2a1 = *(const bf16x8*)(P2b + (size_t)e1.y * 64 + lk * 8);
    const bf16x8 p2c1 = *(const bf16x8*)(P2b + (size_t)e1.y * 64 + 32 + lk * 8);

    // radial weight row (f32), this lane's column chunks
    const float4 w00 = *(const float4*)(We1 + 128 * 64 + lk * 8);
    const float4 w01 = *(const float4*)(We1 + 128 * 64 + lk * 8 + 4);
    const float4 w10 = *(const float4*)(We1 + 128 * 64 + 32 + lk * 8);
    const float4 w11 = *(const float4*)(We1 + 128 * 64 + 32 + lk * 8 + 4);
    const float wv0[8] = {w00.x, w00.y, w00.z, w00.w, w01.x, w01.y, w01.z, w01.w};
    const float wv1[8] = {w10.x, w10.y, w10.z, w10.w, w11.x, w11.y, w11.z, w11.w};

    // geometry
    const float dx0 = cs0.x - cd0.x, dy0 = cs0.y - cd0.y, dz0 = cs0.z - cd0.z;
    const float rad0 = dx0 * dx0 + dy0 * dy0 + dz0 * dz0;
    const float gi0 = fast_rcp(sqrtf(rad0) + EPS_F);
    const float gx0 = dx0 * gi0, gy0 = dy0 * gi0, gz0 = dz0 * gi0;
    const float dx1 = cs1.x - cd1.x, dy1 = cs1.y - cd1.y, dz1 = cs1.z - cd1.z;
    const float rad1 = dx1 * dx1 + dy1 * dy1 + dz1 * dz1;
    const float gi1 = fast_rcp(sqrtf(rad1) + EPS_F);
    const float gx1 = dx1 * gi1, gy1 = dy1 * gi1, gz1 = dz1 * gi1;

    f32x4 acc[4];

    // ================= group 0 =================
    {
        bf16x8 a0, a1;
#pragma unroll
        for (int u = 0; u < 8; ++u) {
            a0[u] = (__bf16)silu_f((float)p1a0[u] + (float)p2a0[u] + rad0 * wv0[u]);
            a1[u] = (__bf16)silu_f((float)p1c0[u] + (float)p2c0[u] + rad0 * wv1[u]);
        }
#pragma unroll
        for (int nt = 0; nt < 4; ++nt) {
            const float b0 = be2[nt * 16 + lr];
            acc[nt] = (f32x4){b0, b0, b0, b0};
            const __bf16* bp = We2p + (size_t)(nt * 16 + lr) * 64 + lk * 8;
            acc[nt] = __builtin_amdgcn_mfma_f32_16x16x32_bf16(a0, *(const bf16x8*)(bp),      acc[nt], 0, 0, 0);
            acc[nt] = __builtin_amdgcn_mfma_f32_16x16x32_bf16(a1, *(const bf16x8*)(bp + 32), acc[nt], 0, 0, 0);
        }
#pragma unroll
        for (int nt = 0; nt < 4; ++nt) {
            const int col = nt * 16 + lr;
#pragma unroll
            for (int r = 0; r < 4; ++r)
                sM[(rbase + lk * 4 + r) * STR2 + col] = (__bf16)silu_f(acc[nt][r]);
        }
        // layer 3 (coef)
        const bf16x8 m0 = *(const bf16x8*)&sM[(rbase + lr) * STR2 + lk * 8];
        const bf16x8 m1 = *(const bf16x8*)&sM[(rbase + lr) * STR2 + 32 + lk * 8];
#pragma unroll
        for (int nt = 0; nt < 4; ++nt) {
            const float b0 = bx1[nt * 16 + lr];
            acc[nt] = (f32x4){b0, b0, b0, b0};
            const __bf16* bp = Wx1p + (size_t)(nt * 16 + lr) * 64 + lk * 8;
            acc[nt] = __builtin_amdgcn_mfma_f32_16x16x32_bf16(m0, *(const bf16x8*)(bp),      acc[nt], 0, 0, 0);
            acc[nt] = __builtin_amdgcn_mfma_f32_16x16x32_bf16(m1, *(const bf16x8*)(bp + 32), acc[nt], 0, 0, 0);
        }
        float p[4] = {0.f, 0.f, 0.f, 0.f};
#pragma unroll
        for (int nt = 0; nt < 4; ++nt) {
            const float wv = Wx2[nt * 16 + lr];
#pragma unroll
            for (int r = 0; r < 4; ++r)
                p[r] += silu_f(acc[nt][r]) * wv;
        }
#pragma unroll
        for (int off = 1; off < 16; off <<= 1)
#pragma unroll
            for (int r = 0; r < 4; ++r)
                p[r] += __shfl_xor(p[r], off);
        if (lr == 0) {
#pragma unroll
            for (int r = 0; r < 4; ++r)
                sCoef[rbase + lk * 4 + r] = p[r];
        }
    }

    // ================= group 1 =================
    {
        bf16x8 a0, a1;
#pragma unroll
        for (int u = 0; u < 8; ++u) {
            a0[u] = (__bf16)silu_f((float)p1a1[u] + (float)p2a1[u] + rad1 * wv0[u]);
            a1[u] = (__bf16)silu_f((float)p1c1[u] + (float)p2c1[u] + rad1 * wv1[u]);
        }
#pragma unroll
        for (int nt = 0; nt < 4; ++nt) {
            const float b0 = be2[nt * 16 + lr];
            acc[nt] = (f32x4){b0, b0, b0, b0};
            const __bf16* bp = We2p + (size_t)(nt * 16 + lr) * 64 + lk * 8;
            acc[nt] = __builtin_amdgcn_mfma_f32_16x16x32_bf16(a0, *(const bf16x8*)(bp),      acc[nt], 0, 0, 0);
            acc[nt] = __builtin_amdgcn_mfma_f32_16x16x32_bf16(a1, *(const bf16x8*)(bp + 32), acc[nt], 0, 0, 0);
        }
#pragma unroll
        for (int nt = 0; nt < 4; ++nt) {
            const int col = nt * 16 + lr;
#pragma unroll
            for (int r = 0; r < 4; ++r)
                sM[(rbase + 16 + lk * 4 + r) * STR2 + col] = (__bf16)silu_f(acc[nt][r]);
        }
        // layer 3 (coef)
        const bf16x8 m0 = *(const bf16x8*)&sM[(rbase + 16 + lr) * STR2 + lk * 8];
        const bf16x8 m1 = *(const bf16x8*)&sM[(rbase + 16 + lr) * STR2 + 32 + lk * 8];
#pragma unroll
        for (int nt = 0; nt < 4; ++nt) {
            const float b0 = bx1[nt * 16 + lr];
            acc[nt] = (f32x4){b0, b0, b0, b0};
            const __bf16* bp = Wx1p + (size_t)(nt * 16 + lr) * 64 + lk * 8;
            acc[nt] = __builtin_amdgcn_mfma_f32_16x16x32_bf16(m0, *(const bf16x8*)(bp),      acc[nt], 0, 0, 0);
            acc[nt] = __builtin_amdgcn_mfma_f32_16x16x32_bf16(m1, *(const bf16x8*)(bp + 32), acc[nt], 0, 0, 0);
        }
        float p[4] = {0.f, 0.f, 0.f, 0.f};
#pragma unroll
        for (int nt = 0; nt < 4; ++nt) {
            const float wv = Wx2[nt * 16 + lr];
#pragma unroll
            for (int r = 0; r < 4; ++r)
                p[r] += silu_f(acc[nt][r]) * wv;
        }
#pragma unroll
        for (int off = 1; off < 16; off <<= 1)
#pragma unroll
            for (int r = 0; r < 4; ++r)
                p[r] += __shfl_xor(p[r], off);
        if (lr == 0) {
#pragma unroll
            for (int r = 0; r < 4; ++r)
                sCoef[rbase + 16 + lk * 4 + r] = p[r];
        }
    }

    // ---- column segment-reduce of 32 msg rows onto h_neigh ----
    {
        float accum = 0.0f;
        int cur = __shfl(e0.y, 0);
#pragma unroll
        for (int rr = 0; rr < 32; ++rr) {
            const int d = (rr < 16) ? __shfl(e0.y, rr) : __shfl(e1.y, rr - 16);
            const float v = (float)sM[(rbase + rr) * STR2 + lane];
            if (d != cur) {                   // wave-uniform branch
                atomicAdd(&h_neigh[(size_t)cur * 64 + lane], accum);
                accum = 0.0f; cur = d;
            }
            accum += v;
        }
        atomicAdd(&h_neigh[(size_t)cur * 64 + lane], accum);
    }

    // ---- xs: in-wave segmented shuffle-reduce, group 0 then group 1 ----
    {
        const float c = sCoef[rbase + lr];
        float vx = c * gx0, vy = c * gy0, vz = c * gz0;
        const int d = e0.y;
#pragma unroll
        for (int off = 1; off < 16; off <<= 1) {
            const int   od = __shfl(d,  lane + off);
            const float ox = __shfl(vx, lane + off);
            const float oy = __shfl(vy, lane + off);
            const float oz = __shfl(vz, lane + off);
            if ((lr + off < 16) && (od == d)) { vx += ox; vy += oy; vz += oz; }
        }
        const int pd = __shfl(d, lane - 1);
        const bool head = (lr == 0) || (pd != d);
        if (head && lk == 0) {
            atomicAdd(&xs[(size_t)d * 4 + 0], vx);
            atomicAdd(&xs[(size_t)d * 4 + 1], vy);
            atomicAdd(&xs[(size_t)d * 4 + 2], vz);
        }
    }
    {
        const float c = sCoef[rbase + 16 + lr];
        float vx = c * gx1, vy = c * gy1, vz = c * gz1;
        const int d = e1.y;
#pragma unroll
        for (int off = 1; off < 16; off <<= 1) {
            const int   od = __shfl(d,  lane + off);
            const float ox = __shfl(vx, lane + off);
            const float oy = __shfl(vy, lane + off);
            const float oz = __shfl(vz, lane + off);
            if ((lr + off < 16) && (od == d)) { vx += ox; vy += oy; vz += oz; }
        }
        const int pd = __shfl(d, lane - 1);
        const bool head = (lr == 0) || (pd != d);
        if (head && lk == 0) {
            atomicAdd(&xs[(size_t)d * 4 + 0], vx);
            atomicAdd(&xs[(size_t)d * 4 + 1], vy);
            atomicAdd(&xs[(size_t)d * 4 + 2], vz);
        }
    }
}

// ---------------- node kernel v6: f32 reads, reg A-fragments ----------------
__global__ __launch_bounds__(256, 8)
void egnn_node_mfma_v6(const float* __restrict__ node_feat,
                       const float* __restrict__ coord,
                       const int* __restrict__ offsets,
                       const float* __restrict__ h_neigh,   // [N*64] f32
                       const float4* __restrict__ xs,       // [N]
                       const float* __restrict__ bn1,
                       const float* __restrict__ bn2,
                       const __bf16* __restrict__ Wn1p,
                       const __bf16* __restrict__ Wn2p,
                       float* __restrict__ out_h,
                       float* __restrict__ out_x)
{
    __shared__ __bf16 sT[64 * STR2];   // wave-private slices

    const int t    = threadIdx.x;
    const int lane = t & 63;
    const int w    = t >> 6;
    const int lr   = lane & 15;
    const int lk   = lane >> 4;
    const int n0   = blockIdx.x * 64;
    const int myrow = n0 + w * 16 + lr;
    const bool valid = (myrow < N_NODES);

    const bf16x8 zf = {(__bf16)0.f, (__bf16)0.f, (__bf16)0.f, (__bf16)0.f,
                       (__bf16)0.f, (__bf16)0.f, (__bf16)0.f, (__bf16)0.f};

    bf16x8 a0 = zf, a1 = zf, a2 = zf, a3 = zf;
    if (valid) {
        const float* np = node_feat + (size_t)myrow * 64;
        a0 = cvt8(*(const float4*)(np + lk * 8),      *(const float4*)(np + lk * 8 + 4));
        a1 = cvt8(*(const float4*)(np + 32 + lk * 8), *(const float4*)(np + 32 + lk * 8 + 4));
        const float* hp = h_neigh + (size_t)myrow * 64;
        a2 = cvt8(*(const float4*)(hp + lk * 8),      *(const float4*)(hp + lk * 8 + 4));
        a3 = cvt8(*(const float4*)(hp + 32 + lk * 8), *(const float4*)(hp + 32 + lk * 8 + 4));
    }

    // coordinate update (first wave, one thread per node)
    if (t < 64) {
        const int n = n0 + t;
        if (n < N_NODES) {
            const int deg = offsets[n + 1] - offsets[n];
            const float inv = fast_rcp(fmaxf((float)deg, 1.0f));
            const float4 xv = xs[n];
            out_x[(size_t)n * 3 + 0] = coord[(size_t)n * 3 + 0] + xv.x * inv;
            out_x[(size_t)n * 3 + 1] = coord[(size_t)n * 3 + 1] + xv.y * inv;
            out_x[(size_t)n * 3 + 2] = coord[(size_t)n * 3 + 2] + xv.z * inv;
        }
    }

    f32x4 acc[4];

    // ---- node layer 1 (K=128) ----
#pragma unroll
    for (int nt = 0; nt < 4; ++nt) {
        const float b0 = bn1[nt * 16 + lr];
        acc[nt] = (f32x4){b0, b0, b0, b0};
        const __bf16* bp = Wn1p + (size_t)(nt * 16 + lr) * 128 + lk * 8;
        acc[nt] = __builtin_amdgcn_mfma_f32_16x16x32_bf16(a0, *(const bf16x8*)(bp),      acc[nt], 0, 0, 0);
        acc[nt] = __builtin_amdgcn_mfma_f32_16x16x32_bf16(a1, *(const bf16x8*)(bp + 32), acc[nt], 0, 0, 0);
        acc[nt] = __builtin_amdgcn_mfma_f32_16x16x32_bf16(a2, *(const bf16x8*)(bp + 64), acc[nt], 0, 0, 0);
        acc[nt] = __builtin_amdgcn_mfma_f32_16x16x32_bf16(a3, *(const bf16x8*)(bp + 96), acc[nt], 0, 0, 0);
    }
#pragma unroll
    for (int nt = 0; nt < 4; ++nt) {
        const int col = nt * 16 + lr;
#pragma unroll
        for (int rr = 0; rr < 4; ++rr)
            sT[(w * 16 + lk * 4 + rr) * STR2 + col] = (__bf16)silu_f(acc[nt][rr]);
    }

    // ---- node layer 2 (K=64), direct stores ----
    {
        const bf16x8 b0f = *(const bf16x8*)&sT[(w * 16 + lr) * STR2 + lk * 8];
        const bf16x8 b1f = *(const bf16x8*)&sT[(w * 16 + lr) * STR2 + 32 + lk * 8];
#pragma unroll
        for (int nt = 0; nt < 4; ++nt) {
            const float b0 = bn2[nt * 16 + lr];
            acc[nt] = (f32x4){b0, b0, b0, b0};
            const __bf16* bp = Wn2p + (size_t)(nt * 16 + lr) * 64 + lk * 8;
            acc[nt] = __builtin_amdgcn_mfma_f32_16x16x32_bf16(b0f, *(const bf16x8*)(bp),      acc[nt], 0, 0, 0);
            acc[nt] = __builtin_amdgcn_mfma_f32_16x16x32_bf16(b1f, *(const bf16x8*)(bp + 32), acc[nt], 0, 0, 0);
        }
#pragma unroll
        for (int nt = 0; nt < 4; ++nt) {
            const int col = nt * 16 + lr;
#pragma unroll
            for (int rr = 0; rr < 4; ++rr) {
                const int row = n0 + w * 16 + lk * 4 + rr;
                if (row < N_NODES)
                    out_h[(size_t)row * 64 + col] = acc[nt][rr];
            }
        }
    }
}

// ================= fallback path (atomics) =================
__global__ void prep_kernel(const float* __restrict__ node_feat,
                            const float* __restrict__ We1,
                            const float* __restrict__ We2,
                            const float* __restrict__ Wx1,
                            const float* __restrict__ Wn1,
                            const float* __restrict__ Wn2,
                            __bf16* __restrict__ nfb,
                            __bf16* __restrict__ We1p,
                            __bf16* __restrict__ We2p,
                            __bf16* __restrict__ Wx1p,
                            __bf16* __restrict__ Wn1p,
                            __bf16* __restrict__ Wn2p)
{
    const int t = blockIdx.x * 256 + threadIdx.x;
    const int stride = gridDim.x * 256;
    for (int i = t; i < N_NODES * 64; i += stride)
        nfb[i] = (__bf16)node_feat[i];
    for (int i = t; i < 64 * 128; i += stride) {
        const int n = i >> 7, k = i & 127;
        We1p[i] = (__bf16)We1[k * 64 + n];
        Wn1p[i] = (__bf16)Wn1[k * 64 + n];
    }
    for (int i = t; i < 64 * 64; i += stride) {
        const int n = i >> 6, k = i & 63;
        We2p[i] = (__bf16)We2[k * 64 + n];
        Wx1p[i] = (__bf16)Wx1[k * 64 + n];
        Wn2p[i] = (__bf16)Wn2[k * 64 + n];
    }
}

__global__ __launch_bounds__(256, 4)
void egnn_edge_mfma_atomic(const float* __restrict__ node_feat,
                           const float* __restrict__ coord,
                           const int* __restrict__ src,
                           const int* __restrict__ dst,
                           const float* __restrict__ We1,
                           const float* __restrict__ be1,
                           const float* __restrict__ be2,
                           const float* __restrict__ bx1,
                           const float* __restrict__ Wx2,
                           const __bf16* __restrict__ We1p,
                           const __bf16* __restrict__ We2p,
                           const __bf16* __restrict__ Wx1p,
                           float* __restrict__ h_neigh,
                           float* __restrict__ x_sum,
                           float* __restrict__ deg)
{
    __shared__ __bf16 sFb[64 * STR1];
    __shared__ __bf16 sT [64 * STR2];
    __shared__ __bf16 sM [64 * STR2];
    __shared__ float  sRad[64];
    __shared__ float  sXd[64][3];
    __shared__ int    sDst[64];

    const int t  = threadIdx.x;
    const int e0 = blockIdx.x * 64;

    {
        const int e = t >> 2, sub = t & 3;
        const int gs = src[e0 + e];
        const int gd = dst[e0 + e];
        const float4* rs = (const float4*)(node_feat + (size_t)gs * 64) + sub * 4;
        const float4* rd = (const float4*)(node_feat + (size_t)gd * 64) + sub * 4;
#pragma unroll
        for (int q = 0; q < 4; ++q) {
            float4 a = rs[q];
            float4 b = rd[q];
            *(bf16x4*)&sFb[e * STR1 + sub * 16 + 4 * q] =
                (bf16x4){(__bf16)a.x, (__bf16)a.y, (__bf16)a.z, (__bf16)a.w};
            *(bf16x4*)&sFb[e * STR1 + 64 + sub * 16 + 4 * q] =
                (bf16x4){(__bf16)b.x, (__bf16)b.y, (__bf16)b.z, (__bf16)b.w};
        }
    }
    if (t < 64) {
        const int e  = t;
        const int gs = src[e0 + e];
        const int gd = dst[e0 + e];
        float dx = coord[(size_t)gs * 3 + 0] - coord[(size_t)gd * 3 + 0];
        float dy = coord[(size_t)gs * 3 + 1] - coord[(size_t)gd * 3 + 1];
        float dz = coord[(size_t)gs * 3 + 2] - coord[(size_t)gd * 3 + 2];
        float radial = dx * dx + dy * dy + dz * dz;
        sRad[e] = radial;
        float inv = fast_rcp(sqrtf(radial) + EPS_F);
        sXd[e][0] = dx * inv; sXd[e][1] = dy * inv; sXd[e][2] = dz * inv;
        sDst[e] = gd;
    }
    __syncthreads();

    const int lane = t & 63;
    const int w    = t >> 6;
    const int lr   = lane & 15;
    const int lk   = lane >> 4;

    f32x4 acc[4];
    {
#pragma unroll
        for (int nt = 0; nt < 4; ++nt) {
            const int col = nt * 16 + lr;
            const float b0 = be1[col];
            const float wr = We1[128 * 64 + col];
#pragma unroll
            for (int r = 0; r < 4; ++r)
                acc[nt][r] = b0 + sRad[w * 16 + lk * 4 + r] * wr;
        }
        const int arow = w * 16 + lr;
#pragma unroll
        for (int ks = 0; ks < 4; ++ks) {
            bf16x8 a = *(const bf16x8*)&sFb[arow * STR1 + ks * 32 + lk * 8];
#pragma unroll
            for (int nt = 0; nt < 4; ++nt) {
                bf16x8 b = *(const bf16x8*)&We1p[(nt * 16 + lr) * 128 + ks * 32 + lk * 8];
                acc[nt] = __builtin_amdgcn_mfma_f32_16x16x32_bf16(a, b, acc[nt], 0, 0, 0);
            }
        }
#pragma unroll
        for (int nt = 0; nt < 4; ++nt) {
            const int col = nt * 16 + lr;
#pragma unroll
            for (int r = 0; r < 4; ++r) {
                const int row = w * 16 + lk * 4 + r;
                sT[row * STR2 + col] = (__bf16)silu_f(acc[nt][r]);
            }
        }
    }
    __syncthreads();
    {
#pragma unroll
        for (int nt = 0; nt < 4; ++nt) {
            const float b0 = be2[nt * 16 + lr];
            acc[nt] = (f32x4){b0, b0, b0, b0};
        }
        const int arow = w * 16 + lr;
#pragma unroll
        for (int ks = 0; ks < 2; ++ks) {
            bf16x8 a = *(const bf16x8*)&sT[arow * STR2 + ks * 32 + lk * 8];
#pragma unroll
            for (int nt = 0; nt < 4; ++nt) {
                bf16x8 b = *(const bf16x8*)&We2p[(nt * 16 + lr) * 64 + ks * 32 + lk * 8];
                acc[nt] = __builtin_amdgcn_mfma_f32_16x16x32_bf16(a, b, acc[nt], 0, 0, 0);
            }
        }
#pragma unroll
        for (int nt = 0; nt < 4; ++nt) {
            const int col = nt * 16 + lr;
#pragma unroll
            for (int r = 0; r < 4; ++r) {
                const int row = w * 16 + lk * 4 + r;
                const float v = silu_f(acc[nt][r]);
                sM[row * STR2 + col] = (__bf16)v;
                atomicAdd(&h_neigh[(size_t)sDst[row] * 64 + col], v);
            }
        }
    }
    __syncthreads();
    {
#pragma unroll
        for (int nt = 0; nt < 4; ++nt) {
            const float b0 = bx1[nt * 16 + lr];
            acc[nt] = (f32x4){b0, b0, b0, b0};
        }
        const int arow = w * 16 + lr;
#pragma unroll
        for (int ks = 0; ks < 2; ++ks) {
            bf16x8 a = *(const bf16x8*)&sM[arow * STR2 + ks * 32 + lk * 8];
#pragma unroll
            for (int nt = 0; nt < 4; ++nt) {
                bf16x8 b = *(const bf16x8*)&Wx1p[(nt * 16 + lr) * 64 + ks * 32 + lk * 8];
                acc[nt] = __builtin_amdgcn_mfma_f32_16x16x32_bf16(a, b, acc[nt], 0, 0, 0);
            }
        }
        float p[4] = {0.f, 0.f, 0.f, 0.f};
#pragma unroll
        for (int nt = 0; nt < 4; ++nt) {
            const float wv = Wx2[nt * 16 + lr];
#pragma unroll
            for (int r = 0; r < 4; ++r)
                p[r] += silu_f(acc[nt][r]) * wv;
        }
#pragma unroll
        for (int off = 1; off < 16; off <<= 1)
#pragma unroll
            for (int r = 0; r < 4; ++r)
                p[r] += __shfl_xor(p[r], off);
        if (lr == 0) {
#pragma unroll
            for (int r = 0; r < 4; ++r) {
                const int e  = w * 16 + lk * 4 + r;
                const int gd = sDst[e];
                const float coef = p[r];
                atomicAdd(&x_sum[(size_t)gd * 3 + 0], coef * sXd[e][0]);
                atomicAdd(&x_sum[(size_t)gd * 3 + 1], coef * sXd[e][1]);
                atomicAdd(&x_sum[(size_t)gd * 3 + 2], coef * sXd[e][2]);
                atomicAdd(&deg[gd], 1.0f);
            }
        }
    }
}

template<int KDIM>
__device__ __forceinline__ void tile_gemm64(const float* __restrict__ A, int astride,
                                            const float* __restrict__ B,
                                            float acc[4][4], int t)
{
    const int tx = t & 15;
    const int ty = t >> 4;
#pragma unroll
    for (int i = 0; i < 4; ++i)
#pragma unroll
        for (int j = 0; j < 4; ++j) acc[i][j] = 0.0f;

    for (int k = 0; k < KDIM; k += 4) {
        float bv[4][4];
#pragma unroll
        for (int kk = 0; kk < 4; ++kk) {
            float4 bq = *(const float4*)(B + (size_t)(k + kk) * 64 + tx * 4);
            bv[kk][0] = bq.x; bv[kk][1] = bq.y; bv[kk][2] = bq.z; bv[kk][3] = bq.w;
        }
#pragma unroll
        for (int i = 0; i < 4; ++i) {
            float4 aq = *(const float4*)(A + (size_t)(ty * 4 + i) * astride + k);
            float av[4] = {aq.x, aq.y, aq.z, aq.w};
#pragma unroll
            for (int kk = 0; kk < 4; ++kk)
#pragma unroll
                for (int j = 0; j < 4; ++j)
                    acc[i][j] = fmaf(av[kk], bv[kk][j], acc[i][j]);
        }
    }
}

__global__ __launch_bounds__(256, 2)
void egnn_node_kernel(const float* __restrict__ node_feat,
                      const float* __restrict__ coord,
                      const float* __restrict__ Wn1, const float* __restrict__ bn1,
                      const float* __restrict__ Wn2, const float* __restrict__ bn2,
                      const float* __restrict__ h_neigh,
                      const float* __restrict__ x_sum,
                      const float* __restrict__ deg,
                      float* __restrict__ out_h,
                      float* __restrict__ out_x)
{
    __shared__ float sF[64][132];
    __shared__ float sT2[64][68];

    const int t  = threadIdx.x;
    const int n0 = blockIdx.x * 64;

    {
        const int r = t >> 2;
        const int sub = t & 3;
        const int n = n0 + r;
        if (n < N_NODES) {
            const float* rowsrc = (sub < 2) ? (node_feat + (size_t)n * 64 + sub * 32)
                                            : (h_neigh  + (size_t)n * 64 + (sub - 2) * 32);
#pragma unroll
            for (int q = 0; q < 8; ++q)
                *(float4*)&sF[r][sub * 32 + 4 * q] = *(const float4*)(rowsrc + 4 * q);
        } else {
#pragma unroll
            for (int q = 0; q < 8; ++q)
                *(float4*)&sF[r][sub * 32 + 4 * q] = make_float4(0.f, 0.f, 0.f, 0.f);
        }
    }
    __syncthreads();

    const int tx = t & 15;
    const int ty = t >> 4;
    float acc[4][4];

    tile_gemm64<128>(&sF[0][0], 132, Wn1, acc, t);
    {
        float4 bq = *(const float4*)(bn1 + tx * 4);
        float bv[4] = {bq.x, bq.y, bq.z, bq.w};
#pragma unroll
        for (int i = 0; i < 4; ++i) {
            float4 o;
            o.x = silu_f(acc[i][0] + bv[0]);
            o.y = silu_f(acc[i][1] + bv[1]);
            o.z = silu_f(acc[i][2] + bv[2]);
            o.w = silu_f(acc[i][3] + bv[3]);
            *(float4*)&sT2[ty * 4 + i][tx * 4] = o;
        }
    }
    __syncthreads();

    tile_gemm64<64>(&sT2[0][0], 68, Wn2, acc, t);
    {
        float4 bq = *(const float4*)(bn2 + tx * 4);
        float bv[4] = {bq.x, bq.y, bq.z, bq.w};
#pragma unroll
        for (int i = 0; i < 4; ++i) {
            const int n = n0 + ty * 4 + i;
            if (n < N_NODES) {
                float4 o;
                o.x = acc[i][0] + bv[0];
                o.y = acc[i][1] + bv[1];
                o.z = acc[i][2] + bv[2];
                o.w = acc[i][3] + bv[3];
                *(float4*)&out_h[(size_t)n * 64 + tx * 4] = o;
            }
        }
    }

    if (t < 64) {
        const int n = n0 + t;
        if (n < N_NODES) {
            const float d = deg[n];
            const float inv = fast_rcp(fmaxf(d, 1.0f));
#pragma unroll
            for (int c = 0; c < 3; ++c)
                out_x[(size_t)n * 3 + c] = coord[(size_t)n * 3 + c]
                                         + x_sum[(size_t)n * 3 + c] * inv;
        }
    }
}

// ================= host =================
extern "C" void kernel_launch(void* const* d_in, const int* in_sizes, int n_in,
                              void* d_out, int out_size, void* d_ws, size_t ws_size,
                              hipStream_t stream) {
    const float* node_feat = (const float*)d_in[0];
    const float* coord     = (const float*)d_in[1];
    const int*   src       = (const int*)d_in[2];
    const int*   dst       = (const int*)d_in[3];
    const float* We1 = (const float*)d_in[4];
    const float* be1 = (const float*)d_in[5];
    const float* We2 = (const float*)d_in[6];
    const float* be2 = (const float*)d_in[7];
    const float* Wx1 = (const float*)d_in[8];
    const float* bx1 = (const float*)d_in[9];
    const float* Wx2 = (const float*)d_in[10];
    const float* Wn1 = (const float*)d_in[11];
    const float* bn1 = (const float*)d_in[12];
    const float* Wn2 = (const float*)d_in[13];
    const float* bn2 = (const float*)d_in[14];

    float* out_h = (float*)d_out;
    float* out_x = out_h + (size_t)N_NODES * 64;

    // ---- workspace layout (fast path); h_neigh/xs/cnt contiguous for ONE memset ----
    char* ws = (char*)d_ws;
    size_t off = 0;
    auto take = [&](size_t bytes) { char* p = ws + off; off = (off + bytes + 255) & ~(size_t)255; return p; };

    float*  h_neigh = (float*)take((size_t)N_NODES * 64 * 4);   // 12.8MB
    float*  xs      = (float*)take((size_t)N_NODES * 16);       // 800KB
    int*    cnt     = (int*)take((size_t)N_NODES * 4);          // 200KB
    const size_t zero_span = off;                                // one memset covers all
    int2*   edge_p  = (int2*)take((size_t)N_EDGES * 8);
    float4* co4     = (float4*)take((size_t)N_NODES * 16);
    __bf16* P1b     = (__bf16*)take((size_t)N_NODES * 64 * 2);
    __bf16* P2b     = (__bf16*)take((size_t)N_NODES * 64 * 2);
    int*    offsets = (int*)take((size_t)(N_NODES + 1) * 4);
    int*    cursor  = (int*)take((size_t)N_NODES * 4);
    int*    excl    = (int*)take((size_t)N_NODES * 4);
    int*    bsum    = (int*)take(1024);
    __bf16* We2p    = (__bf16*)take(64 * 64 * 2);
    __bf16* Wx1p    = (__bf16*)take(64 * 64 * 2);
    __bf16* Wn1p    = (__bf16*)take(64 * 128 * 2);
    __bf16* Wn2p    = (__bf16*)take(64 * 64 * 2);
    const size_t needed = off;

    if (ws_size >= needed) {
        hipMemsetAsync(d_ws, 0, zero_span, stream);

        // one fused launch: pgemm tiles (blocks 0..781) | pack+co4+histogram (rest)
        fused_prep<<<N_TILES + (N_EDGES + 255) / 256, 256, 0, stream>>>(
            node_feat, coord, dst,
            We1, be1, We2, Wx1, Wn1, Wn2,
            We2p, Wx1p, Wn1p, Wn2p, co4, cnt, P1b, P2b);

        scan1_kernel<<<N_CHUNKS, 256, 0, stream>>>(cnt, excl, bsum);
        scan23_kernel<<<N_CHUNKS, 256, 0, stream>>>(bsum, excl, offsets, cursor);
        fill_v4<<<(N_EDGES + 255) / 256, 256, 0, stream>>>(src, dst, cursor, edge_p);

        egnn_edge_mfma_v9<<<N_EDGES / 128, 256, 0, stream>>>(
            P1b, P2b, edge_p, co4,
            We1, be2, bx1, Wx2,
            We2p, Wx1p,
            h_neigh, xs);

        egnn_node_mfma_v6<<<(N_NODES + 63) / 64, 256, 0, stream>>>(
            node_feat, coord, offsets, h_neigh, (const float4*)xs,
            bn1, bn2, Wn1p, Wn2p, out_h, out_x);
    } else {
        // ======== fallback: atomic path ========
        float* fh_neigh = (float*)d_ws;
        float* fx_sum   = fh_neigh + (size_t)N_NODES * 64;
        float* fdeg     = fx_sum + (size_t)N_NODES * 3;
        __bf16* fnfb    = (__bf16*)(fdeg + N_NODES);
        __bf16* fWe1p   = fnfb + (size_t)N_NODES * 64;
        __bf16* fWe2p   = fWe1p + 64 * 128;
        __bf16* fWx1p   = fWe2p + 64 * 64;
        __bf16* fWn1p   = fWx1p + 64 * 64;
        __bf16* fWn2p   = fWn1p + 64 * 128;

        hipMemsetAsync(d_ws, 0, (size_t)N_NODES * 68 * sizeof(float), stream);
        prep_kernel<<<2048, 256, 0, stream>>>(node_feat, We1, We2, Wx1, Wn1, Wn2,
                                              fnfb, fWe1p, fWe2p, fWx1p, fWn1p, fWn2p);
        egnn_edge_mfma_atomic<<<N_EDGES / 64, 256, 0, stream>>>(
            node_feat, coord, src, dst,
            We1, be1, be2, bx1, Wx2,
            fWe1p, fWe2p, fWx1p,
            fh_neigh, fx_sum, fdeg);
        egnn_node_kernel<<<(N_NODES + 63) / 64, 256, 0, stream>>>(
            node_feat, coord, Wn1, bn1, Wn2, bn2,
            fh_neigh, fx_sum, fdeg, out_h, out_x);
    }
}

// Round 15
// 254.705 us; speedup vs baseline: 1.1470x; 1.0055x over previous
//
#include <hip/hip_runtime.h>
#include <math.h>

#define N_NODES 50000
#define N_EDGES 800000
#define EPS_F 1e-30f
#define N_TILES 782     // ceil(N_NODES/64)  (pgemm blocks)
#define N_CHUNKS 196    // ceil(N_NODES/256) (scan chunks)

typedef __bf16 bf16x8 __attribute__((ext_vector_type(8)));
typedef __bf16 bf16x4 __attribute__((ext_vector_type(4)));
typedef float  f32x4  __attribute__((ext_vector_type(4)));

#define STR1 136   // 128-wide bf16 tile row stride (fallback kernel)
#define STR2 72    // 64-wide bf16 tile row stride (144B)

// 1-ulp hardware reciprocal: avoids the IEEE div sequence (~10 VALU ops)
__device__ __forceinline__ float fast_rcp(float x) {
    float r;
    asm("v_rcp_f32 %0, %1" : "=v"(r) : "v"(x));
    return r;
}

__device__ __forceinline__ float silu_f(float x) {
    return x * fast_rcp(1.0f + __expf(-x));
}

__device__ __forceinline__ bf16x8 cvt8(float4 u0, float4 u1) {
    return (bf16x8){(__bf16)u0.x, (__bf16)u0.y, (__bf16)u0.z, (__bf16)u0.w,
                    (__bf16)u1.x, (__bf16)u1.y, (__bf16)u1.z, (__bf16)u1.w};
}

// ---------------- fused prologue: [pgemm tiles | weight pack + co4 + histogram] ----------------
__global__ void fused_prep(const float* __restrict__ node_feat,
                           const float* __restrict__ coord,
                           const int* __restrict__ dst,
                           const float* __restrict__ We1,   // [129][64] f32
                           const float* __restrict__ be1,
                           const float* __restrict__ We2,
                           const float* __restrict__ Wx1,
                           const float* __restrict__ Wn1,
                           const float* __restrict__ Wn2,
                           __bf16* __restrict__ We2p,
                           __bf16* __restrict__ Wx1p,
                           __bf16* __restrict__ Wn1p,
                           __bf16* __restrict__ Wn2p,
                           float4* __restrict__ co4,
                           int* __restrict__ cnt,           // pre-zeroed
                           __bf16* __restrict__ P1b,
                           __bf16* __restrict__ P2b)
{
    __shared__ __bf16 sC[64 * STR2];

    if (blockIdx.x < N_TILES) {
        // ---- pgemm tile: P1 = nf@We1[0:64]+be1, P2 = nf@We1[64:128] ----
        const int t    = threadIdx.x;
        const int lane = t & 63;
        const int w    = t >> 6;
        const int lr   = lane & 15;
        const int lk   = lane >> 4;
        const int n0   = blockIdx.x * 64;
        const int myrow = n0 + w * 16 + lr;
        const bool valid = (myrow < N_NODES);

        const bf16x8 zf = {(__bf16)0.f, (__bf16)0.f, (__bf16)0.f, (__bf16)0.f,
                           (__bf16)0.f, (__bf16)0.f, (__bf16)0.f, (__bf16)0.f};
        bf16x8 a0 = zf, a1 = zf;
        if (valid) {
            const float* np = node_feat + (size_t)myrow * 64;
            a0 = cvt8(*(const float4*)(np + lk * 8),      *(const float4*)(np + lk * 8 + 4));
            a1 = cvt8(*(const float4*)(np + 32 + lk * 8), *(const float4*)(np + 32 + lk * 8 + 4));
        }

        f32x4 acc[4];
#pragma unroll
        for (int pass = 0; pass < 2; ++pass) {
#pragma unroll
            for (int nt = 0; nt < 4; ++nt) {
                const int col = nt * 16 + lr;
                const float b0 = (pass == 0) ? be1[col] : 0.0f;
                acc[nt] = (f32x4){b0, b0, b0, b0};
                // transpose-on-load B fragments from f32 We1 (33KB table, L1-hot)
                const float* wp0 = We1 + (size_t)(pass * 64 + lk * 8) * 64 + col;
                const float* wp1 = wp0 + 32 * 64;
                bf16x8 b0f, b1f;
#pragma unroll
                for (int j = 0; j < 8; ++j) {
                    b0f[j] = (__bf16)wp0[j * 64];
                    b1f[j] = (__bf16)wp1[j * 64];
                }
                acc[nt] = __builtin_amdgcn_mfma_f32_16x16x32_bf16(a0, b0f, acc[nt], 0, 0, 0);
                acc[nt] = __builtin_amdgcn_mfma_f32_16x16x32_bf16(a1, b1f, acc[nt], 0, 0, 0);
            }
#pragma unroll
            for (int nt = 0; nt < 4; ++nt) {
                const int col = nt * 16 + lr;
#pragma unroll
                for (int r = 0; r < 4; ++r)
                    sC[(w * 16 + lk * 4 + r) * STR2 + col] = (__bf16)acc[nt][r];
            }
            if (valid) {
                __bf16* out = (pass == 0) ? P1b : P2b;
                bf16x8 v0 = *(const bf16x8*)&sC[(w * 16 + lr) * STR2 + lk * 8];
                bf16x8 v1 = *(const bf16x8*)&sC[(w * 16 + lr) * STR2 + 32 + lk * 8];
                *(bf16x8*)(out + (size_t)myrow * 64 + lk * 8)      = v0;
                *(bf16x8*)(out + (size_t)myrow * 64 + 32 + lk * 8) = v1;
            }
            __syncthreads();   // sC reuse between passes
        }
    } else {
        // ---- pack weights + co4 + histogram ----
        const int g = blockIdx.x - N_TILES;
        const int t = g * 256 + threadIdx.x;
        const int stride = (gridDim.x - N_TILES) * 256;    // 800000
        for (int i = t; i < 64 * 128; i += stride) {
            const int n = i >> 7, k = i & 127;
            Wn1p[i] = (__bf16)Wn1[k * 64 + n];
        }
        for (int i = t; i < 64 * 64; i += stride) {
            const int n = i >> 6, k = i & 63;
            We2p[i] = (__bf16)We2[k * 64 + n];
            Wx1p[i] = (__bf16)Wx1[k * 64 + n];
            Wn2p[i] = (__bf16)Wn2[k * 64 + n];
        }
        for (int n = t; n < N_NODES; n += stride)
            co4[n] = make_float4(coord[(size_t)n * 3], coord[(size_t)n * 3 + 1],
                                 coord[(size_t)n * 3 + 2], 0.0f);
        if (t < N_EDGES) atomicAdd(&cnt[dst[t]], 1);
    }
}

// ---------------- CSR scan: chunk scan then fused (bsum-scan + offsets) ----------------
__global__ void scan1_kernel(const int* __restrict__ cnt,
                             int* __restrict__ excl, int* __restrict__ bsum) {
    __shared__ int s[256];
    const int tid = threadIdx.x;
    const int i = blockIdx.x * 256 + tid;
    const int v = (i < N_NODES) ? cnt[i] : 0;
    s[tid] = v; __syncthreads();
#pragma unroll
    for (int off = 1; off < 256; off <<= 1) {
        int t = (tid >= off) ? s[tid - off] : 0;
        __syncthreads();
        s[tid] += t;
        __syncthreads();
    }
    if (i < N_NODES) excl[i] = s[tid] - v;
    if (tid == 255) bsum[blockIdx.x] = s[255];
}

__global__ void scan23_kernel(const int* __restrict__ bsum,
                              const int* __restrict__ excl,
                              int* __restrict__ offsets, int* __restrict__ cursor) {
    __shared__ int s[256];
    __shared__ int base;
    const int tid = threadIdx.x;
    const int bid = blockIdx.x;
    const int v = (tid < N_CHUNKS) ? bsum[tid] : 0;
    s[tid] = v; __syncthreads();
#pragma unroll
    for (int off = 1; off < 256; off <<= 1) {
        int t = (tid >= off) ? s[tid - off] : 0;
        __syncthreads();
        s[tid] += t;
        __syncthreads();
    }
    if (tid == 0) base = (bid > 0) ? s[bid - 1] : 0;
    __syncthreads();
    const int i = bid * 256 + tid;
    if (i < N_NODES) {
        const int o = base + excl[i];
        offsets[i] = o;
        cursor[i] = o;
    }
    if (bid == 0 && tid == 0) offsets[N_NODES] = N_EDGES;
}

__global__ void fill_v4(const int* __restrict__ src, const int* __restrict__ dst,
                        int* __restrict__ cursor,
                        int2* __restrict__ edge_p) {
    const int e = blockIdx.x * 256 + threadIdx.x;
    if (e < N_EDGES) {
        const int gs = src[e];
        const int gd = dst[e];
        const int p = atomicAdd(&cursor[gd], 1);
        edge_p[p] = make_int2(gs, gd);
    }
}

// ---------------- edge kernel v12: 2-edge ILP, (256,5) for 20 waves/CU ----------------
__global__ __launch_bounds__(256, 5)
void egnn_edge_mfma_v12(const __bf16* __restrict__ P1b,
                        const __bf16* __restrict__ P2b,
                        const int2* __restrict__ edge_p,
                        const float4* __restrict__ co4,
                        const float* __restrict__ We1,   // row 128 (radial) f32
                        const float* __restrict__ be2,
                        const float* __restrict__ bx1,
                        const float* __restrict__ Wx2,
                        const __bf16* __restrict__ We2p,
                        const __bf16* __restrict__ Wx1p,
                        float* __restrict__ h_neigh,     // [N*64] f32 accum
                        float* __restrict__ xs)          // [N*4]  f32 accum
{
    // wave-private LDS only (wave w owns rows w*32 .. w*32+31)
    __shared__ __bf16 sM[128 * STR2];
    __shared__ float  sCoef[128];

    const int t     = threadIdx.x;
    const int lane  = t & 63;
    const int w     = t >> 6;
    const int lr    = lane & 15;
    const int lk    = lane >> 4;
    const int j0    = blockIdx.x * 128;    // E = 6250*128, no tail
    const int rbase = w * 32;

    const int2 e0 = edge_p[j0 + rbase + lr];
    const int2 e1 = edge_p[j0 + rbase + 16 + lr];

    // ---- issue all scattered loads up front (two independent chains) ----
    const float4 cs0 = co4[e0.x], cd0 = co4[e0.y];
    const float4 cs1 = co4[e1.x], cd1 = co4[e1.y];
    const bf16x8 p1a0 = *(const bf16x8*)(P1b + (size_t)e0.x * 64 + lk * 8);
    const bf16x8 p1c0 = *(const bf16x8*)(P1b + (size_t)e0.x * 64 + 32 + lk * 8);
    const bf16x8 p2a0 = *(const bf16x8*)(P2b + (size_t)e0.y * 64 + lk * 8);
    const bf16x8 p2c0 = *(const bf16x8*)(P2b + (size_t)e0.y * 64 + 32 + lk * 8);
    const bf16x8 p1a1 = *(const bf16x8*)(P1b + (size_t)e1.x * 64 + lk * 8);
    const bf16x8 p1c1 = *(const bf16x8*)(P1b + (size_t)e1.x * 64 + 32 + lk * 8);
    const bf16x8 p2a1 = *(const bf16x8*)(P2b + (size_t)e1.y * 64 + lk * 8);
    const bf16x8 p2c1 = *(const bf16x8*)(P2b + (size_t)e1.y * 64 + 32 + lk * 8);

    // radial weight row (f32), this lane's column chunks
    const float4 w00 = *(const float4*)(We1 + 128 * 64 + lk * 8);
    const float4 w01 = *(const float4*)(We1 + 128 * 64 + lk * 8 + 4);
    const float4 w10 = *(const float4*)(We1 + 128 * 64 + 32 + lk * 8);
    const float4 w11 = *(const float4*)(We1 + 128 * 64 + 32 + lk * 8 + 4);
    const float wv0[8] = {w00.x, w00.y, w00.z, w00.w, w01.x, w01.y, w01.z, w01.w};
    const float wv1[8] = {w10.x, w10.y, w10.z, w10.w, w11.x, w11.y, w11.z, w11.w};

    // geometry
    const float dx0 = cs0.x - cd0.x, dy0 = cs0.y - cd0.y, dz0 = cs0.z - cd0.z;
    const float rad0 = dx0 * dx0 + dy0 * dy0 + dz0 * dz0;
    const float gi0 = fast_rcp(sqrtf(rad0) + EPS_F);
    const float gx0 = dx0 * gi0, gy0 = dy0 * gi0, gz0 = dz0 * gi0;
    const float dx1 = cs1.x - cd1.x, dy1 = cs1.y - cd1.y, dz1 = cs1.z - cd1.z;
    const float rad1 = dx1 * dx1 + dy1 * dy1 + dz1 * dz1;
    const float gi1 = fast_rcp(sqrtf(rad1) + EPS_F);
    const float gx1 = dx1 * gi1, gy1 = dy1 * gi1, gz1 = dz1 * gi1;

    f32x4 acc[4];

    // ================= group 0 =================
    {
        bf16x8 a0, a1;
#pragma unroll
        for (int u = 0; u < 8; ++u) {
            a0[u] = (__bf16)silu_f((float)p1a0[u] + (float)p2a0[u] + rad0 * wv0[u]);
            a1[u] = (__bf16)silu_f((float)p1c0[u] + (float)p2c0[u] + rad0 * wv1[u]);
        }
#pragma unroll
        for (int nt = 0; nt < 4; ++nt) {
            const float b0 = be2[nt * 16 + lr];
            acc[nt] = (f32x4){b0, b0, b0, b0};
            const __bf16* bp = We2p + (size_t)(nt * 16 + lr) * 64 + lk * 8;
            acc[nt] = __builtin_amdgcn_mfma_f32_16x16x32_bf16(a0, *(const bf16x8*)(bp),      acc[nt], 0, 0, 0);
            acc[nt] = __builtin_amdgcn_mfma_f32_16x16x32_bf16(a1, *(const bf16x8*)(bp + 32), acc[nt], 0, 0, 0);
        }
#pragma unroll
        for (int nt = 0; nt < 4; ++nt) {
            const int col = nt * 16 + lr;
#pragma unroll
            for (int r = 0; r < 4; ++r)
                sM[(rbase + lk * 4 + r) * STR2 + col] = (__bf16)silu_f(acc[nt][r]);
        }
        // layer 3 (coef)
        const bf16x8 m0 = *(const bf16x8*)&sM[(rbase + lr) * STR2 + lk * 8];
        const bf16x8 m1 = *(const bf16x8*)&sM[(rbase + lr) * STR2 + 32 + lk * 8];
#pragma unroll
        for (int nt = 0; nt < 4; ++nt) {
            const float b0 = bx1[nt * 16 + lr];
            acc[nt] = (f32x4){b0, b0, b0, b0};
            const __bf16* bp = Wx1p + (size_t)(nt * 16 + lr) * 64 + lk * 8;
            acc[nt] = __builtin_amdgcn_mfma_f32_16x16x32_bf16(m0, *(const bf16x8*)(bp),      acc[nt], 0, 0, 0);
            acc[nt] = __builtin_amdgcn_mfma_f32_16x16x32_bf16(m1, *(const bf16x8*)(bp + 32), acc[nt], 0, 0, 0);
        }
        float p[4] = {0.f, 0.f, 0.f, 0.f};
#pragma unroll
        for (int nt = 0; nt < 4; ++nt) {
            const float wv = Wx2[nt * 16 + lr];
#pragma unroll
            for (int r = 0; r < 4; ++r)
                p[r] += silu_f(acc[nt][r]) * wv;
        }
#pragma unroll
        for (int off = 1; off < 16; off <<= 1)
#pragma unroll
            for (int r = 0; r < 4; ++r)
                p[r] += __shfl_xor(p[r], off);
        if (lr == 0) {
#pragma unroll
            for (int r = 0; r < 4; ++r)
                sCoef[rbase + lk * 4 + r] = p[r];
        }
    }

    // ================= group 1 =================
    {
        bf16x8 a0, a1;
#pragma unroll
        for (int u = 0; u < 8; ++u) {
            a0[u] = (__bf16)silu_f((float)p1a1[u] + (float)p2a1[u] + rad1 * wv0[u]);
            a1[u] = (__bf16)silu_f((float)p1c1[u] + (float)p2c1[u] + rad1 * wv1[u]);
        }
#pragma unroll
        for (int nt = 0; nt < 4; ++nt) {
            const float b0 = be2[nt * 16 + lr];
            acc[nt] = (f32x4){b0, b0, b0, b0};
            const __bf16* bp = We2p + (size_t)(nt * 16 + lr) * 64 + lk * 8;
            acc[nt] = __builtin_amdgcn_mfma_f32_16x16x32_bf16(a0, *(const bf16x8*)(bp),      acc[nt], 0, 0, 0);
            acc[nt] = __builtin_amdgcn_mfma_f32_16x16x32_bf16(a1, *(const bf16x8*)(bp + 32), acc[nt], 0, 0, 0);
        }
#pragma unroll
        for (int nt = 0; nt < 4; ++nt) {
            const int col = nt * 16 + lr;
#pragma unroll
            for (int r = 0; r < 4; ++r)
                sM[(rbase + 16 + lk * 4 + r) * STR2 + col] = (__bf16)silu_f(acc[nt][r]);
        }
        // layer 3 (coef)
        const bf16x8 m0 = *(const bf16x8*)&sM[(rbase + 16 + lr) * STR2 + lk * 8];
        const bf16x8 m1 = *(const bf16x8*)&sM[(rbase + 16 + lr) * STR2 + 32 + lk * 8];
#pragma unroll
        for (int nt = 0; nt < 4; ++nt) {
            const float b0 = bx1[nt * 16 + lr];
            acc[nt] = (f32x4){b0, b0, b0, b0};
            const __bf16* bp = Wx1p + (size_t)(nt * 16 + lr) * 64 + lk * 8;
            acc[nt] = __builtin_amdgcn_mfma_f32_16x16x32_bf16(m0, *(const bf16x8*)(bp),      acc[nt], 0, 0, 0);
            acc[nt] = __builtin_amdgcn_mfma_f32_16x16x32_bf16(m1, *(const bf16x8*)(bp + 32), acc[nt], 0, 0, 0);
        }
        float p[4] = {0.f, 0.f, 0.f, 0.f};
#pragma unroll
        for (int nt = 0; nt < 4; ++nt) {
            const float wv = Wx2[nt * 16 + lr];
#pragma unroll
            for (int r = 0; r < 4; ++r)
                p[r] += silu_f(acc[nt][r]) * wv;
        }
#pragma unroll
        for (int off = 1; off < 16; off <<= 1)
#pragma unroll
            for (int r = 0; r < 4; ++r)
                p[r] += __shfl_xor(p[r], off);
        if (lr == 0) {
#pragma unroll
            for (int r = 0; r < 4; ++r)
                sCoef[rbase + 16 + lk * 4 + r] = p[r];
        }
    }

    // ---- column segment-reduce of 32 msg rows onto h_neigh ----
    {
        float accum = 0.0f;
        int cur = __shfl(e0.y, 0);
#pragma unroll
        for (int rr = 0; rr < 32; ++rr) {
            const int d = (rr < 16) ? __shfl(e0.y, rr) : __shfl(e1.y, rr - 16);
            const float v = (float)sM[(rbase + rr) * STR2 + lane];
            if (d != cur) {                   // wave-uniform branch
                atomicAdd(&h_neigh[(size_t)cur * 64 + lane], accum);
                accum = 0.0f; cur = d;
            }
            accum += v;
        }
        atomicAdd(&h_neigh[(size_t)cur * 64 + lane], accum);
    }

    // ---- xs: in-wave segmented shuffle-reduce, group 0 then group 1 ----
    {
        const float c = sCoef[rbase + lr];
        float vx = c * gx0, vy = c * gy0, vz = c * gz0;
        const int d = e0.y;
#pragma unroll
        for (int off = 1; off < 16; off <<= 1) {
            const int   od = __shfl(d,  lane + off);
            const float ox = __shfl(vx, lane + off);
            const float oy = __shfl(vy, lane + off);
            const float oz = __shfl(vz, lane + off);
            if ((lr + off < 16) && (od == d)) { vx += ox; vy += oy; vz += oz; }
        }
        const int pd = __shfl(d, lane - 1);
        const bool head = (lr == 0) || (pd != d);
        if (head && lk == 0) {
            atomicAdd(&xs[(size_t)d * 4 + 0], vx);
            atomicAdd(&xs[(size_t)d * 4 + 1], vy);
            atomicAdd(&xs[(size_t)d * 4 + 2], vz);
        }
    }
    {
        const float c = sCoef[rbase + 16 + lr];
        float vx = c * gx1, vy = c * gy1, vz = c * gz1;
        const int d = e1.y;
#pragma unroll
        for (int off = 1; off < 16; off <<= 1) {
            const int   od = __shfl(d,  lane + off);
            const float ox = __shfl(vx, lane + off);
            const float oy = __shfl(vy, lane + off);
            const float oz = __shfl(vz, lane + off);
            if ((lr + off < 16) && (od == d)) { vx += ox; vy += oy; vz += oz; }
        }
        const int pd = __shfl(d, lane - 1);
        const bool head = (lr == 0) || (pd != d);
        if (head && lk == 0) {
            atomicAdd(&xs[(size_t)d * 4 + 0], vx);
            atomicAdd(&xs[(size_t)d * 4 + 1], vy);
            atomicAdd(&xs[(size_t)d * 4 + 2], vz);
        }
    }
}

// ---------------- node kernel v6: f32 reads, reg A-fragments ----------------
__global__ __launch_bounds__(256, 8)
void egnn_node_mfma_v6(const float* __restrict__ node_feat,
                       const float* __restrict__ coord,
                       const int* __restrict__ offsets,
                       const float* __restrict__ h_neigh,   // [N*64] f32
                       const float4* __restrict__ xs,       // [N]
                       const float* __restrict__ bn1,
                       const float* __restrict__ bn2,
                       const __bf16* __restrict__ Wn1p,
                       const __bf16* __restrict__ Wn2p,
                       float* __restrict__ out_h,
                       float* __restrict__ out_x)
{
    __shared__ __bf16 sT[64 * STR2];   // wave-private slices

    const int t    = threadIdx.x;
    const int lane = t & 63;
    const int w    = t >> 6;
    const int lr   = lane & 15;
    const int lk   = lane >> 4;
    const int n0   = blockIdx.x * 64;
    const int myrow = n0 + w * 16 + lr;
    const bool valid = (myrow < N_NODES);

    const bf16x8 zf = {(__bf16)0.f, (__bf16)0.f, (__bf16)0.f, (__bf16)0.f,
                       (__bf16)0.f, (__bf16)0.f, (__bf16)0.f, (__bf16)0.f};

    bf16x8 a0 = zf, a1 = zf, a2 = zf, a3 = zf;
    if (valid) {
        const float* np = node_feat + (size_t)myrow * 64;
        a0 = cvt8(*(const float4*)(np + lk * 8),      *(const float4*)(np + lk * 8 + 4));
        a1 = cvt8(*(const float4*)(np + 32 + lk * 8), *(const float4*)(np + 32 + lk * 8 + 4));
        const float* hp = h_neigh + (size_t)myrow * 64;
        a2 = cvt8(*(const float4*)(hp + lk * 8),      *(const float4*)(hp + lk * 8 + 4));
        a3 = cvt8(*(const float4*)(hp + 32 + lk * 8), *(const float4*)(hp + 32 + lk * 8 + 4));
    }

    // coordinate update (first wave, one thread per node)
    if (t < 64) {
        const int n = n0 + t;
        if (n < N_NODES) {
            const int deg = offsets[n + 1] - offsets[n];
            const float inv = fast_rcp(fmaxf((float)deg, 1.0f));
            const float4 xv = xs[n];
            out_x[(size_t)n * 3 + 0] = coord[(size_t)n * 3 + 0] + xv.x * inv;
            out_x[(size_t)n * 3 + 1] = coord[(size_t)n * 3 + 1] + xv.y * inv;
            out_x[(size_t)n * 3 + 2] = coord[(size_t)n * 3 + 2] + xv.z * inv;
        }
    }

    f32x4 acc[4];

    // ---- node layer 1 (K=128) ----
#pragma unroll
    for (int nt = 0; nt < 4; ++nt) {
        const float b0 = bn1[nt * 16 + lr];
        acc[nt] = (f32x4){b0, b0, b0, b0};
        const __bf16* bp = Wn1p + (size_t)(nt * 16 + lr) * 128 + lk * 8;
        acc[nt] = __builtin_amdgcn_mfma_f32_16x16x32_bf16(a0, *(const bf16x8*)(bp),      acc[nt], 0, 0, 0);
        acc[nt] = __builtin_amdgcn_mfma_f32_16x16x32_bf16(a1, *(const bf16x8*)(bp + 32), acc[nt], 0, 0, 0);
        acc[nt] = __builtin_amdgcn_mfma_f32_16x16x32_bf16(a2, *(const bf16x8*)(bp + 64), acc[nt], 0, 0, 0);
        acc[nt] = __builtin_amdgcn_mfma_f32_16x16x32_bf16(a3, *(const bf16x8*)(bp + 96), acc[nt], 0, 0, 0);
    }
#pragma unroll
    for (int nt = 0; nt < 4; ++nt) {
        const int col = nt * 16 + lr;
#pragma unroll
        for (int rr = 0; rr < 4; ++rr)
            sT[(w * 16 + lk * 4 + rr) * STR2 + col] = (__bf16)silu_f(acc[nt][rr]);
    }

    // ---- node layer 2 (K=64), direct stores ----
    {
        const bf16x8 b0f = *(const bf16x8*)&sT[(w * 16 + lr) * STR2 + lk * 8];
        const bf16x8 b1f = *(const bf16x8*)&sT[(w * 16 + lr) * STR2 + 32 + lk * 8];
#pragma unroll
        for (int nt = 0; nt < 4; ++nt) {
            const float b0 = bn2[nt * 16 + lr];
            acc[nt] = (f32x4){b0, b0, b0, b0};
            const __bf16* bp = Wn2p + (size_t)(nt * 16 + lr) * 64 + lk * 8;
            acc[nt] = __builtin_amdgcn_mfma_f32_16x16x32_bf16(b0f, *(const bf16x8*)(bp),      acc[nt], 0, 0, 0);
            acc[nt] = __builtin_amdgcn_mfma_f32_16x16x32_bf16(b1f, *(const bf16x8*)(bp + 32), acc[nt], 0, 0, 0);
        }
#pragma unroll
        for (int nt = 0; nt < 4; ++nt) {
            const int col = nt * 16 + lr;
#pragma unroll
            for (int rr = 0; rr < 4; ++rr) {
                const int row = n0 + w * 16 + lk * 4 + rr;
                if (row < N_NODES)
                    out_h[(size_t)row * 64 + col] = acc[nt][rr];
            }
        }
    }
}

// ================= fallback path (atomics) =================
__global__ void prep_kernel(const float* __restrict__ node_feat,
                            const float* __restrict__ We1,
                            const float* __restrict__ We2,
                            const float* __restrict__ Wx1,
                            const float* __restrict__ Wn1,
                            const float* __restrict__ Wn2,
                            __bf16* __restrict__ nfb,
                            __bf16* __restrict__ We1p,
                            __bf16* __restrict__ We2p,
                            __bf16* __restrict__ Wx1p,
                            __bf16* __restrict__ Wn1p,
                            __bf16* __restrict__ Wn2p)
{
    const int t = blockIdx.x * 256 + threadIdx.x;
    const int stride = gridDim.x * 256;
    for (int i = t; i < N_NODES * 64; i += stride)
        nfb[i] = (__bf16)node_feat[i];
    for (int i = t; i < 64 * 128; i += stride) {
        const int n = i >> 7, k = i & 127;
        We1p[i] = (__bf16)We1[k * 64 + n];
        Wn1p[i] = (__bf16)Wn1[k * 64 + n];
    }
    for (int i = t; i < 64 * 64; i += stride) {
        const int n = i >> 6, k = i & 63;
        We2p[i] = (__bf16)We2[k * 64 + n];
        Wx1p[i] = (__bf16)Wx1[k * 64 + n];
        Wn2p[i] = (__bf16)Wn2[k * 64 + n];
    }
}

__global__ __launch_bounds__(256, 4)
void egnn_edge_mfma_atomic(const float* __restrict__ node_feat,
                           const float* __restrict__ coord,
                           const int* __restrict__ src,
                           const int* __restrict__ dst,
                           const float* __restrict__ We1,
                           const float* __restrict__ be1,
                           const float* __restrict__ be2,
                           const float* __restrict__ bx1,
                           const float* __restrict__ Wx2,
                           const __bf16* __restrict__ We1p,
                           const __bf16* __restrict__ We2p,
                           const __bf16* __restrict__ Wx1p,
                           float* __restrict__ h_neigh,
                           float* __restrict__ x_sum,
                           float* __restrict__ deg)
{
    __shared__ __bf16 sFb[64 * STR1];
    __shared__ __bf16 sT [64 * STR2];
    __shared__ __bf16 sM [64 * STR2];
    __shared__ float  sRad[64];
    __shared__ float  sXd[64][3];
    __shared__ int    sDst[64];

    const int t  = threadIdx.x;
    const int e0 = blockIdx.x * 64;

    {
        const int e = t >> 2, sub = t & 3;
        const int gs = src[e0 + e];
        const int gd = dst[e0 + e];
        const float4* rs = (const float4*)(node_feat + (size_t)gs * 64) + sub * 4;
        const float4* rd = (const float4*)(node_feat + (size_t)gd * 64) + sub * 4;
#pragma unroll
        for (int q = 0; q < 4; ++q) {
            float4 a = rs[q];
            float4 b = rd[q];
            *(bf16x4*)&sFb[e * STR1 + sub * 16 + 4 * q] =
                (bf16x4){(__bf16)a.x, (__bf16)a.y, (__bf16)a.z, (__bf16)a.w};
            *(bf16x4*)&sFb[e * STR1 + 64 + sub * 16 + 4 * q] =
                (bf16x4){(__bf16)b.x, (__bf16)b.y, (__bf16)b.z, (__bf16)b.w};
        }
    }
    if (t < 64) {
        const int e  = t;
        const int gs = src[e0 + e];
        const int gd = dst[e0 + e];
        float dx = coord[(size_t)gs * 3 + 0] - coord[(size_t)gd * 3 + 0];
        float dy = coord[(size_t)gs * 3 + 1] - coord[(size_t)gd * 3 + 1];
        float dz = coord[(size_t)gs * 3 + 2] - coord[(size_t)gd * 3 + 2];
        float radial = dx * dx + dy * dy + dz * dz;
        sRad[e] = radial;
        float inv = fast_rcp(sqrtf(radial) + EPS_F);
        sXd[e][0] = dx * inv; sXd[e][1] = dy * inv; sXd[e][2] = dz * inv;
        sDst[e] = gd;
    }
    __syncthreads();

    const int lane = t & 63;
    const int w    = t >> 6;
    const int lr   = lane & 15;
    const int lk   = lane >> 4;

    f32x4 acc[4];
    {
#pragma unroll
        for (int nt = 0; nt < 4; ++nt) {
            const int col = nt * 16 + lr;
            const float b0 = be1[col];
            const float wr = We1[128 * 64 + col];
#pragma unroll
            for (int r = 0; r < 4; ++r)
                acc[nt][r] = b0 + sRad[w * 16 + lk * 4 + r] * wr;
        }
        const int arow = w * 16 + lr;
#pragma unroll
        for (int ks = 0; ks < 4; ++ks) {
            bf16x8 a = *(const bf16x8*)&sFb[arow * STR1 + ks * 32 + lk * 8];
#pragma unroll
            for (int nt = 0; nt < 4; ++nt) {
                bf16x8 b = *(const bf16x8*)&We1p[(nt * 16 + lr) * 128 + ks * 32 + lk * 8];
                acc[nt] = __builtin_amdgcn_mfma_f32_16x16x32_bf16(a, b, acc[nt], 0, 0, 0);
            }
        }
#pragma unroll
        for (int nt = 0; nt < 4; ++nt) {
            const int col = nt * 16 + lr;
#pragma unroll
            for (int r = 0; r < 4; ++r) {
                const int row = w * 16 + lk * 4 + r;
                sT[row * STR2 + col] = (__bf16)silu_f(acc[nt][r]);
            }
        }
    }
    __syncthreads();
    {
#pragma unroll
        for (int nt = 0; nt < 4; ++nt) {
            const float b0 = be2[nt * 16 + lr];
            acc[nt] = (f32x4){b0, b0, b0, b0};
        }
        const int arow = w * 16 + lr;
#pragma unroll
        for (int ks = 0; ks < 2; ++ks) {
            bf16x8 a = *(const bf16x8*)&sT[arow * STR2 + ks * 32 + lk * 8];
#pragma unroll
            for (int nt = 0; nt < 4; ++nt) {
                bf16x8 b = *(const bf16x8*)&We2p[(nt * 16 + lr) * 64 + ks * 32 + lk * 8];
                acc[nt] = __builtin_amdgcn_mfma_f32_16x16x32_bf16(a, b, acc[nt], 0, 0, 0);
            }
        }
#pragma unroll
        for (int nt = 0; nt < 4; ++nt) {
            const int col = nt * 16 + lr;
#pragma unroll
            for (int r = 0; r < 4; ++r) {
                const int row = w * 16 + lk * 4 + r;
                const float v = silu_f(acc[nt][r]);
                sM[row * STR2 + col] = (__bf16)v;
                atomicAdd(&h_neigh[(size_t)sDst[row] * 64 + col], v);
            }
        }
    }
    __syncthreads();
    {
#pragma unroll
        for (int nt = 0; nt < 4; ++nt) {
            const float b0 = bx1[nt * 16 + lr];
            acc[nt] = (f32x4){b0, b0, b0, b0};
        }
        const int arow = w * 16 + lr;
#pragma unroll
        for (int ks = 0; ks < 2; ++ks) {
            bf16x8 a = *(const bf16x8*)&sM[arow * STR2 + ks * 32 + lk * 8];
#pragma unroll
            for (int nt = 0; nt < 4; ++nt) {
                bf16x8 b = *(const bf16x8*)&Wx1p[(nt * 16 + lr) * 64 + ks * 32 + lk * 8];
                acc[nt] = __builtin_amdgcn_mfma_f32_16x16x32_bf16(a, b, acc[nt], 0, 0, 0);
            }
        }
        float p[4] = {0.f, 0.f, 0.f, 0.f};
#pragma unroll
        for (int nt = 0; nt < 4; ++nt) {
            const float wv = Wx2[nt * 16 + lr];
#pragma unroll
            for (int r = 0; r < 4; ++r)
                p[r] += silu_f(acc[nt][r]) * wv;
        }
#pragma unroll
        for (int off = 1; off < 16; off <<= 1)
#pragma unroll
            for (int r = 0; r < 4; ++r)
                p[r] += __shfl_xor(p[r], off);
        if (lr == 0) {
#pragma unroll
            for (int r = 0; r < 4; ++r) {
                const int e  = w * 16 + lk * 4 + r;
                const int gd = sDst[e];
                const float coef = p[r];
                atomicAdd(&x_sum[(size_t)gd * 3 + 0], coef * sXd[e][0]);
                atomicAdd(&x_sum[(size_t)gd * 3 + 1], coef * sXd[e][1]);
                atomicAdd(&x_sum[(size_t)gd * 3 + 2], coef * sXd[e][2]);
                atomicAdd(&deg[gd], 1.0f);
            }
        }
    }
}

template<int KDIM>
__device__ __forceinline__ void tile_gemm64(const float* __restrict__ A, int astride,
                                            const float* __restrict__ B,
                                            float acc[4][4], int t)
{
    const int tx = t & 15;
    const int ty = t >> 4;
#pragma unroll
    for (int i = 0; i < 4; ++i)
#pragma unroll
        for (int j = 0; j < 4; ++j) acc[i][j] = 0.0f;

    for (int k = 0; k < KDIM; k += 4) {
        float bv[4][4];
#pragma unroll
        for (int kk = 0; kk < 4; ++kk) {
            float4 bq = *(const float4*)(B + (size_t)(k + kk) * 64 + tx * 4);
            bv[kk][0] = bq.x; bv[kk][1] = bq.y; bv[kk][2] = bq.z; bv[kk][3] = bq.w;
        }
#pragma unroll
        for (int i = 0; i < 4; ++i) {
            float4 aq = *(const float4*)(A + (size_t)(ty * 4 + i) * astride + k);
            float av[4] = {aq.x, aq.y, aq.z, aq.w};
#pragma unroll
            for (int kk = 0; kk < 4; ++kk)
#pragma unroll
                for (int j = 0; j < 4; ++j)
                    acc[i][j] = fmaf(av[kk], bv[kk][j], acc[i][j]);
        }
    }
}

__global__ __launch_bounds__(256, 2)
void egnn_node_kernel(const float* __restrict__ node_feat,
                      const float* __restrict__ coord,
                      const float* __restrict__ Wn1, const float* __restrict__ bn1,
                      const float* __restrict__ Wn2, const float* __restrict__ bn2,
                      const float* __restrict__ h_neigh,
                      const float* __restrict__ x_sum,
                      const float* __restrict__ deg,
                      float* __restrict__ out_h,
                      float* __restrict__ out_x)
{
    __shared__ float sF[64][132];
    __shared__ float sT2[64][68];

    const int t  = threadIdx.x;
    const int n0 = blockIdx.x * 64;

    {
        const int r = t >> 2;
        const int sub = t & 3;
        const int n = n0 + r;
        if (n < N_NODES) {
            const float* rowsrc = (sub < 2) ? (node_feat + (size_t)n * 64 + sub * 32)
                                            : (h_neigh  + (size_t)n * 64 + (sub - 2) * 32);
#pragma unroll
            for (int q = 0; q < 8; ++q)
                *(float4*)&sF[r][sub * 32 + 4 * q] = *(const float4*)(rowsrc + 4 * q);
        } else {
#pragma unroll
            for (int q = 0; q < 8; ++q)
                *(float4*)&sF[r][sub * 32 + 4 * q] = make_float4(0.f, 0.f, 0.f, 0.f);
        }
    }
    __syncthreads();

    const int tx = t & 15;
    const int ty = t >> 4;
    float acc[4][4];

    tile_gemm64<128>(&sF[0][0], 132, Wn1, acc, t);
    {
        float4 bq = *(const float4*)(bn1 + tx * 4);
        float bv[4] = {bq.x, bq.y, bq.z, bq.w};
#pragma unroll
        for (int i = 0; i < 4; ++i) {
            float4 o;
            o.x = silu_f(acc[i][0] + bv[0]);
            o.y = silu_f(acc[i][1] + bv[1]);
            o.z = silu_f(acc[i][2] + bv[2]);
            o.w = silu_f(acc[i][3] + bv[3]);
            *(float4*)&sT2[ty * 4 + i][tx * 4] = o;
        }
    }
    __syncthreads();

    tile_gemm64<64>(&sT2[0][0], 68, Wn2, acc, t);
    {
        float4 bq = *(const float4*)(bn2 + tx * 4);
        float bv[4] = {bq.x, bq.y, bq.z, bq.w};
#pragma unroll
        for (int i = 0; i < 4; ++i) {
            const int n = n0 + ty * 4 + i;
            if (n < N_NODES) {
                float4 o;
                o.x = acc[i][0] + bv[0];
                o.y = acc[i][1] + bv[1];
                o.z = acc[i][2] + bv[2];
                o.w = acc[i][3] + bv[3];
                *(float4*)&out_h[(size_t)n * 64 + tx * 4] = o;
            }
        }
    }

    if (t < 64) {
        const int n = n0 + t;
        if (n < N_NODES) {
            const float d = deg[n];
            const float inv = fast_rcp(fmaxf(d, 1.0f));
#pragma unroll
            for (int c = 0; c < 3; ++c)
                out_x[(size_t)n * 3 + c] = coord[(size_t)n * 3 + c]
                                         + x_sum[(size_t)n * 3 + c] * inv;
        }
    }
}

// ================= host =================
extern "C" void kernel_launch(void* const* d_in, const int* in_sizes, int n_in,
                              void* d_out, int out_size, void* d_ws, size_t ws_size,
                              hipStream_t stream) {
    const float* node_feat = (const float*)d_in[0];
    const float* coord     = (const float*)d_in[1];
    const int*   src       = (const int*)d_in[2];
    const int*   dst       = (const int*)d_in[3];
    const float* We1 = (const float*)d_in[4];
    const float* be1 = (const float*)d_in[5];
    const float* We2 = (const float*)d_in[6];
    const float* be2 = (const float*)d_in[7];
    const float* Wx1 = (const float*)d_in[8];
    const float* bx1 = (const float*)d_in[9];
    const float* Wx2 = (const float*)d_in[10];
    const float* Wn1 = (const float*)d_in[11];
    const float* bn1 = (const float*)d_in[12];
    const float* Wn2 = (const float*)d_in[13];
    const float* bn2 = (const float*)d_in[14];

    float* out_h = (float*)d_out;
    float* out_x = out_h + (size_t)N_NODES * 64;

    // ---- workspace layout (fast path); h_neigh/xs/cnt contiguous for ONE memset ----
    char* ws = (char*)d_ws;
    size_t off = 0;
    auto take = [&](size_t bytes) { char* p = ws + off; off = (off + bytes + 255) & ~(size_t)255; return p; };

    float*  h_neigh = (float*)take((size_t)N_NODES * 64 * 4);   // 12.8MB
    float*  xs      = (float*)take((size_t)N_NODES * 16);       // 800KB
    int*    cnt     = (int*)take((size_t)N_NODES * 4);          // 200KB
    const size_t zero_span = off;                                // one memset covers all
    int2*   edge_p  = (int2*)take((size_t)N_EDGES * 8);
    float4* co4     = (float4*)take((size_t)N_NODES * 16);
    __bf16* P1b     = (__bf16*)take((size_t)N_NODES * 64 * 2);
    __bf16* P2b     = (__bf16*)take((size_t)N_NODES * 64 * 2);
    int*    offsets = (int*)take((size_t)(N_NODES + 1) * 4);
    int*    cursor  = (int*)take((size_t)N_NODES * 4);
    int*    excl    = (int*)take((size_t)N_NODES * 4);
    int*    bsum    = (int*)take(1024);
    __bf16* We2p    = (__bf16*)take(64 * 64 * 2);
    __bf16* Wx1p    = (__bf16*)take(64 * 64 * 2);
    __bf16* Wn1p    = (__bf16*)take(64 * 128 * 2);
    __bf16* Wn2p    = (__bf16*)take(64 * 64 * 2);
    const size_t needed = off;

    if (ws_size >= needed) {
        hipMemsetAsync(d_ws, 0, zero_span, stream);

        // one fused launch: pgemm tiles (blocks 0..781) | pack+co4+histogram (rest)
        fused_prep<<<N_TILES + (N_EDGES + 255) / 256, 256, 0, stream>>>(
            node_feat, coord, dst,
            We1, be1, We2, Wx1, Wn1, Wn2,
            We2p, Wx1p, Wn1p, Wn2p, co4, cnt, P1b, P2b);

        scan1_kernel<<<N_CHUNKS, 256, 0, stream>>>(cnt, excl, bsum);
        scan23_kernel<<<N_CHUNKS, 256, 0, stream>>>(bsum, excl, offsets, cursor);
        fill_v4<<<(N_EDGES + 255) / 256, 256, 0, stream>>>(src, dst, cursor, edge_p);

        egnn_edge_mfma_v12<<<N_EDGES / 128, 256, 0, stream>>>(
            P1b, P2b, edge_p, co4,
            We1, be2, bx1, Wx2,
            We2p, Wx1p,
            h_neigh, xs);

        egnn_node_mfma_v6<<<(N_NODES + 63) / 64, 256, 0, stream>>>(
            node_feat, coord, offsets, h_neigh, (const float4*)xs,
            bn1, bn2, Wn1p, Wn2p, out_h, out_x);
    } else {
        // ======== fallback: atomic path ========
        float* fh_neigh = (float*)d_ws;
        float* fx_sum   = fh_neigh + (size_t)N_NODES * 64;
        float* fdeg     = fx_sum + (size_t)N_NODES * 3;
        __bf16* fnfb    = (__bf16*)(fdeg + N_NODES);
        __bf16* fWe1p   = fnfb + (size_t)N_NODES * 64;
        __bf16* fWe2p   = fWe1p + 64 * 128;
        __bf16* fWx1p   = fWe2p + 64 * 64;
        __bf16* fWn1p   = fWx1p + 64 * 64;
        __bf16* fWn2p   = fWn1p + 64 * 128;

        hipMemsetAsync(d_ws, 0, (size_t)N_NODES * 68 * sizeof(float), stream);
        prep_kernel<<<2048, 256, 0, stream>>>(node_feat, We1, We2, Wx1, Wn1, Wn2,
                                              fnfb, fWe1p, fWe2p, fWx1p, fWn1p, fWn2p);
        egnn_edge_mfma_atomic<<<N_EDGES / 64, 256, 0, stream>>>(
            node_feat, coord, src, dst,
            We1, be1, be2, bx1, Wx2,
            fWe1p, fWe2p, fWx1p,
            fh_neigh, fx_sum, fdeg);
        egnn_node_kernel<<<(N_NODES + 63) / 64, 256, 0, stream>>>(
            node_feat, coord, Wn1, bn1, Wn2, bn2,
            fh_neigh, fx_sum, fdeg, out_h, out_x);
    }
}